// Round 1
// baseline (1365.897 us; speedup 1.0000x reference)
//
#include <hip/hip_runtime.h>
#include <hip/hip_bf16.h>
#include <math.h>

#define NNODE 3000
#define NCHUNK 47  // ceil(3000/64)
#define ALPHA 0.2f
#define NEGV -9.0e15f

// ---------------- adj -> bitmask ----------------
__global__ __launch_bounds__(256)
void k_bitmask(const int* __restrict__ adj, unsigned long long* __restrict__ bm) {
  int row = blockIdx.x * 4 + (threadIdx.x >> 6);
  int lane = threadIdx.x & 63;
  if (row >= 2 * NNODE) return;
  const int* arow = adj + (size_t)row * NNODE;
  unsigned long long* brow = bm + (size_t)row * NCHUNK;
  for (int c = 0; c < NCHUNK; ++c) {
    int m = c * 64 + lane;
    int v = (m < NNODE) ? (arow[m] > 0) : 0;
    unsigned long long mask = __ballot(v);
    if (lane == 0) brow[c] = mask;
  }
}

// ---------------- generic tiled fp32 GEMM ----------------
// C[z][m,n] = act( sum_k A[z][m,k] * B[z][k,n or n,k] + bias[n] )
template <int BM, int BN, int BK, int TM, int TN, bool BT, int ACT>
__global__ __launch_bounds__((BM / TM) * (BN / TN))
void k_gemm(const float* __restrict__ A, long long boffA, int ldA,
            const float* __restrict__ B, long long boffB,
            const float* __restrict__ bias,
            float* __restrict__ C, long long boffC, int ldC,
            int M, int N, int K) {
  constexpr int NT = (BM / TM) * (BN / TN);
  constexpr int NCG = BN / TN;
  const int z = blockIdx.z;
  A += boffA * z;
  B += boffB * z;
  C += boffC * z;
  const int m0 = blockIdx.x * BM;
  const int n0 = blockIdx.y * BN;
  __shared__ float As[BK][BM + 4];
  __shared__ float Bs[BK][BN + 4];
  const int tid = threadIdx.x;
  const int trow = tid / NCG, tcol = tid % NCG;
  float acc[TM][TN] = {};
  for (int k0 = 0; k0 < K; k0 += BK) {
    for (int i = tid; i < BM * BK; i += NT) {
      int r = i / BK, c = i % BK;
      int gm = m0 + r;
      As[c][r] = (gm < M) ? A[(size_t)gm * ldA + (k0 + c)] : 0.f;
    }
    if (!BT) {
      for (int i = tid; i < BK * BN; i += NT) {
        int r = i / BN, c = i % BN;
        Bs[r][c] = B[(size_t)(k0 + r) * N + (n0 + c)];
      }
    } else {
      for (int i = tid; i < BK * BN; i += NT) {
        int r = i % BK, c = i / BK;
        Bs[r][c] = B[(size_t)(n0 + c) * K + (k0 + r)];
      }
    }
    __syncthreads();
#pragma unroll 8
    for (int kk = 0; kk < BK; ++kk) {
      float ar[TM], br[TN];
#pragma unroll
      for (int i2 = 0; i2 < TM; ++i2) ar[i2] = As[kk][trow * TM + i2];
#pragma unroll
      for (int j = 0; j < TN; ++j) br[j] = Bs[kk][tcol * TN + j];
#pragma unroll
      for (int i2 = 0; i2 < TM; ++i2)
#pragma unroll
        for (int j = 0; j < TN; ++j)
          acc[i2][j] = fmaf(ar[i2], br[j], acc[i2][j]);
    }
    __syncthreads();
  }
#pragma unroll
  for (int i2 = 0; i2 < TM; ++i2) {
    int gm = m0 + trow * TM + i2;
    if (gm >= M) continue;
#pragma unroll
    for (int j = 0; j < TN; ++j) {
      int gn = n0 + tcol * TN + j;
      float v = acc[i2][j];
      if (bias) v += bias[gn];
      if (ACT == 1) v = v > 0.f ? v : (__expf(v) - 1.f);
      C[(size_t)gm * ldC + gn] = v;
    }
  }
}

// ---------------- f1/f2 = Wh . a ----------------
__global__ __launch_bounds__(256)
void k_f12(const float* __restrict__ Wh, const float* __restrict__ avec,
           float* __restrict__ f1, float* __restrict__ f2, int O) {
  int row = blockIdx.x * 4 + (threadIdx.x >> 6);
  int lane = threadIdx.x & 63;
  if (row >= 8 * NNODE) return;
  int z = row / NNODE;
  const float* w = Wh + (size_t)row * O;
  const float* av = avec + (size_t)z * 2 * O;
  float s1 = 0.f, s2 = 0.f;
  for (int o = lane; o < O; o += 64) {
    float v = w[o];
    s1 += v * av[o];
    s2 += v * av[O + o];
  }
  for (int off = 32; off; off >>= 1) {
    s1 += __shfl_down(s1, off);
    s2 += __shfl_down(s2, off);
  }
  if (lane == 0) {
    f1[row] = s1;
    f2[row] = s2;
  }
}

// ---------------- exact softmax stats (rowmax, rowsum) ----------------
__global__ __launch_bounds__(256)
void k_stats(const float* __restrict__ f1, const float* __restrict__ f2,
             const unsigned long long* __restrict__ bm,
             float* __restrict__ rmax, float* __restrict__ rsum) {
  int row = blockIdx.x * 4 + (threadIdx.x >> 6);
  int lane = threadIdx.x & 63;
  if (row >= 8 * NNODE) return;
  int z = row / NNODE;          // a*4+h
  int a = z >> 2;
  int n = row % NNODE;
  const unsigned long long* brow = bm + ((size_t)a * NNODE + n) * NCHUNK;
  const float* f2r = f2 + (size_t)z * NNODE;
  float f1n = f1[row];
  float mx = -3.0e38f;
  for (int c = 0; c < NCHUNK; ++c) {
    unsigned long long w = brow[c];
    int m = c * 64 + lane;
    if (m < NNODE) {
      float sc;
      if ((w >> lane) & 1ULL) {
        float e = f1n + f2r[m];
        sc = e > 0.f ? e : ALPHA * e;
      } else
        sc = NEGV;
      mx = fmaxf(mx, sc);
    }
  }
  for (int off = 32; off; off >>= 1) mx = fmaxf(mx, __shfl_xor(mx, off));
  float sm = 0.f;
  for (int c = 0; c < NCHUNK; ++c) {
    unsigned long long w = brow[c];
    int m = c * 64 + lane;
    if (m < NNODE) {
      float sc;
      if ((w >> lane) & 1ULL) {
        float e = f1n + f2r[m];
        sc = e > 0.f ? e : ALPHA * e;
      } else
        sc = NEGV;
      sm += __expf(sc - mx);
    }
  }
  for (int off = 32; off; off >>= 1) sm += __shfl_xor(sm, off);
  if (lane == 0) {
    rmax[row] = mx;
    rsum[row] = sm;
  }
}

// ---------------- PV: C[a][n][h*O+o] = elu( softmax(P) @ Wh ) ----------------
template <int O, int TM, int TN>
__global__ __launch_bounds__(256)
void k_pv(const float* __restrict__ Wh, const float* __restrict__ f1,
          const float* __restrict__ f2, const float* __restrict__ rmax,
          const float* __restrict__ rsum,
          const unsigned long long* __restrict__ bm, float* __restrict__ Cc) {
  constexpr int BM = 64, BK = 64;
  constexpr int NCG = O / TN;
  const int z = blockIdx.z;
  const int a = z >> 2, h = z & 3;
  const int n0 = blockIdx.x * BM;
  const float* WhB = Wh + (size_t)z * NNODE * O;
  const float* f2B = f2 + (size_t)z * NNODE;
  __shared__ float Ps[BK][BM + 4];   // P^T : [k][row]
  __shared__ float Whs[BK][O + 4];
  __shared__ float F1s[BM], Rms[BM], Rsi[BM];
  __shared__ unsigned long long Bw[BM];
  const int tid = threadIdx.x;
  const int trow = tid / NCG, tcol = tid % NCG;
  if (tid < BM) {
    int n = n0 + tid;
    bool v = n < NNODE;
    F1s[tid] = v ? f1[(size_t)z * NNODE + n] : 0.f;
    Rms[tid] = v ? rmax[(size_t)z * NNODE + n] : 0.f;
    Rsi[tid] = v ? 1.f / rsum[(size_t)z * NNODE + n] : 1.f;
  }
  float acc[TM][TN] = {};
  for (int k0 = 0; k0 < NNODE; k0 += BK) {
    if (tid < BM) {
      int n = n0 + tid;
      Bw[tid] = (n < NNODE) ? bm[((size_t)a * NNODE + n) * NCHUNK + (k0 >> 6)] : 0ULL;
    }
    for (int i = tid; i < BK * O; i += 256) {
      int r = i / O, c = i % O;
      int m = k0 + r;
      Whs[r][c] = (m < NNODE) ? WhB[(size_t)m * O + c] : 0.f;
    }
    __syncthreads();
    for (int i = tid; i < BM * BK; i += 256) {
      int r = i % BM, c = i / BM;
      int m = k0 + c;
      float p = 0.f;
      if (m < NNODE) {
        float sc;
        if ((Bw[r] >> c) & 1ULL) {
          float e = F1s[r] + f2B[m];
          sc = e > 0.f ? e : ALPHA * e;
        } else
          sc = NEGV;
        p = __expf(sc - Rms[r]);
      }
      Ps[c][r] = p;
    }
    __syncthreads();
#pragma unroll 8
    for (int kk = 0; kk < BK; ++kk) {
      float ar[TM], br[TN];
#pragma unroll
      for (int i2 = 0; i2 < TM; ++i2) ar[i2] = Ps[kk][trow * TM + i2];
#pragma unroll
      for (int j = 0; j < TN; ++j) br[j] = Whs[kk][tcol * TN + j];
#pragma unroll
      for (int i2 = 0; i2 < TM; ++i2)
#pragma unroll
        for (int j = 0; j < TN; ++j)
          acc[i2][j] = fmaf(ar[i2], br[j], acc[i2][j]);
    }
    __syncthreads();
  }
#pragma unroll
  for (int i2 = 0; i2 < TM; ++i2) {
    int r = trow * TM + i2;
    int n = n0 + r;
    if (n >= NNODE) continue;
#pragma unroll
    for (int j = 0; j < TN; ++j) {
      float v = acc[i2][j] * Rsi[r];
      v = v > 0.f ? v : (__expf(v) - 1.f);
      Cc[(size_t)a * NNODE * 4 * O + (size_t)n * 4 * O + h * O + tcol * TN + j] = v;
    }
  }
}

// ---------------- log_softmax rows of 8 ----------------
__global__ __launch_bounds__(256)
void k_lsm(const float* __restrict__ out2, float* __restrict__ out) {
  int n = blockIdx.x * blockDim.x + threadIdx.x;
  if (n >= NNODE) return;
  const float* r = out2 + (size_t)n * 8;
  float mx = r[0];
#pragma unroll
  for (int j = 1; j < 8; ++j) mx = fmaxf(mx, r[j]);
  float s = 0.f;
#pragma unroll
  for (int j = 0; j < 8; ++j) s += __expf(r[j] - mx);
  float ls = __logf(s) + mx;
#pragma unroll
  for (int j = 0; j < 8; ++j) out[(size_t)n * 8 + j] = r[j] - ls;
}

// ---------------- L1 scalar ----------------
__global__ __launch_bounds__(256)
void k_l1(const float* __restrict__ wfus1, const float* __restrict__ wfus2,
          float* __restrict__ o) {
  __shared__ float red[256];
  int tid = threadIdx.x;
  float s1 = 0.f, s2 = 0.f;
  for (int i = tid; i < 64 * 128; i += 256) s1 += fabsf(wfus1[i]);
  if (tid < 128) s2 = fabsf(wfus2[tid]);
  red[tid] = s1 / 8192.f + s2 / 128.f;
  __syncthreads();
  for (int off = 128; off; off >>= 1) {
    if (tid < off) red[tid] += red[tid + off];
    __syncthreads();
  }
  if (tid == 0) o[0] = red[0];
}

extern "C" void kernel_launch(void* const* d_in, const int* in_sizes, int n_in,
                              void* d_out, int out_size, void* d_ws, size_t ws_size,
                              hipStream_t stream) {
  const float* x = (const float*)d_in[0];
  const int* adj = (const int*)d_in[1];
  const float* W1 = (const float*)d_in[2];
  const float* a1 = (const float*)d_in[3];
  const float* W2 = (const float*)d_in[4];
  const float* a2 = (const float*)d_in[5];
  const float* wint1 = (const float*)d_in[6];
  const float* bint1 = (const float*)d_in[7];
  const float* wfus1 = (const float*)d_in[8];
  const float* bfus1 = (const float*)d_in[9];
  const float* wint2 = (const float*)d_in[10];
  const float* bint2 = (const float*)d_in[11];
  const float* wfus2 = (const float*)d_in[12];
  const float* bfus2 = (const float*)d_in[13];
  float* out = (float*)d_out;

  float* Wh1 = (float*)d_ws;                 // [8][3000][64]
  float* h1cat = Wh1 + 1536000;              // [2][3000][256]
  float* f1b = h1cat + 1536000;              // [8][3000]
  float* f2b = f1b + 24000;
  float* rmx = f2b + 24000;
  float* rsm = rmx + 24000;
  float* t1 = rsm + 24000;                   // [3000][128]
  float* out1 = t1 + 384000;                 // [3000][64]
  float* Wh2 = out1 + 192000;                // [8][3000][32]
  float* h2cat = Wh2 + 768000;               // [2][3000][128]
  float* t2 = h2cat + 768000;                // [3000][16]
  float* out2 = t2 + 48000;                  // [3000][8]
  unsigned long long* bm = (unsigned long long*)(out2 + 24000);  // [2][3000][47]

  // adj -> bitmask
  k_bitmask<<<dim3((2 * NNODE + 3) / 4), 256, 0, stream>>>(adj, bm);

  // Wh1 = x @ W1 per (a,h)
  k_gemm<64, 64, 32, 4, 4, false, 0><<<dim3(47, 1, 8), 256, 0, stream>>>(
      x, 0, 512, W1, 512 * 64, nullptr, Wh1, (long long)NNODE * 64, 64, NNODE, 64, 512);

  // f1/f2 stage 1
  k_f12<<<dim3(6000), 256, 0, stream>>>(Wh1, a1, f1b, f2b, 64);
  // softmax stats stage 1
  k_stats<<<dim3(6000), 256, 0, stream>>>(f1b, f2b, bm, rmx, rsm);
  // PV stage 1 -> h1cat
  k_pv<64, 4, 4><<<dim3(47, 1, 8), 256, 0, stream>>>(Wh1, f1b, f2b, rmx, rsm, bm, h1cat);

  // int1: t1[n][a*64+g] = elu(h1cat @ wint1^T + bint1)
  k_gemm<64, 64, 32, 4, 4, true, 1><<<dim3(47, 1, 2), 256, 0, stream>>>(
      h1cat, (long long)NNODE * 256, 256, wint1, 0, bint1, t1, 64, 128, NNODE, 64, 256);
  // fus1: out1 = t1 @ wfus1^T + bfus1
  k_gemm<64, 64, 32, 4, 4, true, 0><<<dim3(47, 1, 1), 256, 0, stream>>>(
      t1, 0, 128, wfus1, 0, bfus1, out1, 0, 64, NNODE, 64, 128);

  // Wh2 = out1 @ W2 per (a,h)
  k_gemm<64, 32, 32, 4, 2, false, 0><<<dim3(47, 1, 8), 256, 0, stream>>>(
      out1, 0, 64, W2, 64 * 32, nullptr, Wh2, (long long)NNODE * 32, 32, NNODE, 32, 64);

  // f1/f2 stage 2
  k_f12<<<dim3(6000), 256, 0, stream>>>(Wh2, a2, f1b, f2b, 32);
  k_stats<<<dim3(6000), 256, 0, stream>>>(f1b, f2b, bm, rmx, rsm);
  // PV stage 2 -> h2cat
  k_pv<32, 4, 2><<<dim3(47, 1, 8), 256, 0, stream>>>(Wh2, f1b, f2b, rmx, rsm, bm, h2cat);

  // int2: t2[n][a*8+c] = elu(h2cat @ wint2^T + bint2)
  k_gemm<64, 8, 32, 2, 1, true, 1><<<dim3(47, 1, 2), 256, 0, stream>>>(
      h2cat, (long long)NNODE * 128, 128, wint2, 0, bint2, t2, 8, 16, NNODE, 8, 128);
  // fus2: out2 = t2 @ wfus2^T + bfus2
  k_gemm<64, 8, 16, 2, 1, true, 0><<<dim3(47, 1, 1), 256, 0, stream>>>(
      t2, 0, 16, wfus2, 0, bfus2, out2, 0, 8, NNODE, 8, 16);

  // log_softmax -> out[0..23999]
  k_lsm<<<dim3((NNODE + 255) / 256), 256, 0, stream>>>(out2, out);
  // l1 scalar -> out[24000]
  k_l1<<<dim3(1), 256, 0, stream>>>(wfus1, wfus2, out + 24000);
}

// Round 3
// 681.322 us; speedup vs baseline: 2.0048x; 2.0048x over previous
//
#include <hip/hip_runtime.h>
#include <hip/hip_bf16.h>
#include <math.h>

#define NNODE 3000
#define NCHUNK 47  // ceil(3000/64)
#define ALPHA 0.2f

// ---------------- adj -> bitmask ----------------
__global__ __launch_bounds__(256)
void k_bitmask(const int* __restrict__ adj, unsigned long long* __restrict__ bm) {
  int row = blockIdx.x * 4 + (threadIdx.x >> 6);
  int lane = threadIdx.x & 63;
  if (row >= 2 * NNODE) return;
  const int* arow = adj + (size_t)row * NNODE;
  unsigned long long* brow = bm + (size_t)row * NCHUNK;
  for (int c = 0; c < NCHUNK; ++c) {
    int m = c * 64 + lane;
    int v = (m < NNODE) ? (arow[m] > 0) : 0;
    unsigned long long mask = __ballot(v);
    if (lane == 0) brow[c] = mask;
  }
}

// ---------------- generic tiled fp32 GEMM ----------------
template <int BM, int BN, int BK, int TM, int TN, bool BT, int ACT>
__global__ __launch_bounds__((BM / TM) * (BN / TN))
void k_gemm(const float* __restrict__ A, long long boffA, int ldA,
            const float* __restrict__ B, long long boffB,
            const float* __restrict__ bias,
            float* __restrict__ C, long long boffC, int ldC,
            int M, int N, int K) {
  constexpr int NT = (BM / TM) * (BN / TN);
  constexpr int NCG = BN / TN;
  const int z = blockIdx.z;
  A += boffA * z;
  B += boffB * z;
  C += boffC * z;
  const int m0 = blockIdx.x * BM;
  const int n0 = blockIdx.y * BN;
  __shared__ float As[BK][BM + 4];
  __shared__ float Bs[BK][BN + 4];
  const int tid = threadIdx.x;
  const int trow = tid / NCG, tcol = tid % NCG;
  float acc[TM][TN] = {};
  for (int k0 = 0; k0 < K; k0 += BK) {
    for (int i = tid; i < BM * BK; i += NT) {
      int r = i / BK, c = i % BK;
      int gm = m0 + r;
      As[c][r] = (gm < M) ? A[(size_t)gm * ldA + (k0 + c)] : 0.f;
    }
    if (!BT) {
      for (int i = tid; i < BK * BN; i += NT) {
        int r = i / BN, c = i % BN;
        Bs[r][c] = B[(size_t)(k0 + r) * N + (n0 + c)];
      }
    } else {
      for (int i = tid; i < BK * BN; i += NT) {
        int r = i % BK, c = i / BK;
        Bs[r][c] = B[(size_t)(n0 + c) * K + (k0 + r)];
      }
    }
    __syncthreads();
#pragma unroll 8
    for (int kk = 0; kk < BK; ++kk) {
      float ar[TM], br[TN];
#pragma unroll
      for (int i2 = 0; i2 < TM; ++i2) ar[i2] = As[kk][trow * TM + i2];
#pragma unroll
      for (int j = 0; j < TN; ++j) br[j] = Bs[kk][tcol * TN + j];
#pragma unroll
      for (int i2 = 0; i2 < TM; ++i2)
#pragma unroll
        for (int j = 0; j < TN; ++j)
          acc[i2][j] = fmaf(ar[i2], br[j], acc[i2][j]);
    }
    __syncthreads();
  }
#pragma unroll
  for (int i2 = 0; i2 < TM; ++i2) {
    int gm = m0 + trow * TM + i2;
    if (gm >= M) continue;
#pragma unroll
    for (int j = 0; j < TN; ++j) {
      int gn = n0 + tcol * TN + j;
      float v = acc[i2][j];
      if (bias) v += bias[gn];
      if (ACT == 1) v = v > 0.f ? v : (__expf(v) - 1.f);
      C[(size_t)gm * ldC + gn] = v;
    }
  }
}

// ---------------- f1/f2 = Wh . a ----------------
__global__ __launch_bounds__(256)
void k_f12(const float* __restrict__ Wh, const float* __restrict__ avec,
           float* __restrict__ f1, float* __restrict__ f2, int O) {
  int row = blockIdx.x * 4 + (threadIdx.x >> 6);
  int lane = threadIdx.x & 63;
  if (row >= 8 * NNODE) return;
  int z = row / NNODE;
  const float* w = Wh + (size_t)row * O;
  const float* av = avec + (size_t)z * 2 * O;
  float s1 = 0.f, s2 = 0.f;
  for (int o = lane; o < O; o += 64) {
    float v = w[o];
    s1 += v * av[o];
    s2 += v * av[O + o];
  }
  for (int off = 32; off; off >>= 1) {
    s1 += __shfl_down(s1, off);
    s2 += __shfl_down(s2, off);
  }
  if (lane == 0) {
    f1[row] = s1;
    f2[row] = s2;
  }
}

// ---------------- fused PV: unnormalized P + in-block rowsum ----------------
// Block: 64 rows x OW cols, full K sweep. P = exp(lrelu(f1+f2)) if adj else 0.
// Epilogue: /rowsum, ELU, scatter to head-concat layout.
template <int O, int OW, int TN>
__global__ __launch_bounds__(256)
void k_pvf(const float* __restrict__ Wh, const float* __restrict__ f1,
           const float* __restrict__ f2,
           const unsigned long long* __restrict__ bm,
           float* __restrict__ Cc) {
  constexpr int BM = 64, BK = 64, TM = 4;
  constexpr int NCG = OW / TN;  // 16
  constexpr int HO = 4 * O;
  const int z = blockIdx.z, a = z >> 2, h = z & 3;
  const int ocol0 = blockIdx.y * OW;
  const int n0 = blockIdx.x * BM;
  const float* WhB = Wh + (size_t)z * NNODE * O;
  const float* f2B = f2 + (size_t)z * NNODE;
  __shared__ float Ps[BK][BM + 4];
  __shared__ float Whs[BK][OW + 4];
  __shared__ float F1s[BM];
  __shared__ float F2s[BK];
  __shared__ float RSt[BM];
  __shared__ unsigned long long Bw[BM];
  __shared__ float RSred[4][BM];
  const int tid = threadIdx.x;
  const int trow = tid / NCG, tcol = tid % NCG;
  const int prow = tid & 63, pcg = tid >> 6;
  if (tid < BM) {
    int n = n0 + tid;
    F1s[tid] = (n < NNODE) ? f1[(size_t)z * NNODE + n] : 0.f;
  }
  float acc[TM][TN] = {};
  float rs = 0.f;
  const unsigned long long* bmA = bm + (size_t)a * NNODE * NCHUNK;
  for (int k0 = 0; k0 < NNODE; k0 += BK) {
    // stage masks + f2 tile (disjoint from Ps/Whs -> safe vs prev FMA)
    if (tid < BM) {
      int n = n0 + tid;
      Bw[tid] = (n < NNODE) ? bmA[(size_t)n * NCHUNK + (k0 >> 6)] : 0ULL;
      int m = k0 + tid;
      F2s[tid] = (m < NNODE) ? f2B[m] : 0.f;
    }
    __syncthreads();  // (A) prev FMA done; Bw/F2s visible
    // stage Wh tile (vectorized)
    for (int i = tid; i < BK * OW / 4; i += 256) {
      int r = i / (OW / 4), vc = i % (OW / 4);
      int m = k0 + r;
      float4 v = make_float4(0.f, 0.f, 0.f, 0.f);
      if (m < NNODE)
        v = *reinterpret_cast<const float4*>(&WhB[(size_t)m * O + ocol0 + vc * 4]);
      *reinterpret_cast<float4*>(&Whs[r][vc * 4]) = v;
    }
    // generate P tile (and accumulate rowsum)
    {
      unsigned long long bwr = Bw[prow];
      float f1v = F1s[prow];
#pragma unroll
      for (int j = 0; j < 16; ++j) {
        int c = pcg + j * 4;
        float p = 0.f;
        if ((bwr >> c) & 1ULL) {
          float e = f1v + F2s[c];
          e = fmaxf(e, ALPHA * e);  // leaky-relu (alpha<1)
          p = __expf(e);
        }
        Ps[c][prow] = p;
        rs += p;
      }
    }
    __syncthreads();  // (B) Ps+Whs ready
#pragma unroll 8
    for (int kk = 0; kk < BK; ++kk) {
      const float4 ar = *reinterpret_cast<const float4*>(&Ps[kk][trow * TM]);
      float av[TM] = {ar.x, ar.y, ar.z, ar.w};
      float bv[TN];
#pragma unroll
      for (int j = 0; j < TN; ++j) bv[j] = Whs[kk][tcol * TN + j];
#pragma unroll
      for (int i2 = 0; i2 < TM; ++i2)
#pragma unroll
        for (int j = 0; j < TN; ++j)
          acc[i2][j] = fmaf(av[i2], bv[j], acc[i2][j]);
    }
  }
  // rowsum 4-way reduce
  RSred[pcg][prow] = rs;
  __syncthreads();
  if (tid < BM) {
    float s = RSred[0][tid] + RSred[1][tid] + RSred[2][tid] + RSred[3][tid];
    RSt[tid] = (s > 0.f) ? 1.f / s : 0.f;
  }
  __syncthreads();
#pragma unroll
  for (int i2 = 0; i2 < TM; ++i2) {
    int r = trow * TM + i2;
    int n = n0 + r;
    if (n >= NNODE) continue;
    float inv = RSt[r];
#pragma unroll
    for (int j = 0; j < TN; ++j) {
      float v = acc[i2][j] * inv;
      v = v > 0.f ? v : (__expf(v) - 1.f);
      Cc[((size_t)a * NNODE + n) * HO + h * O + ocol0 + tcol * TN + j] = v;
    }
  }
}

// ---------------- log_softmax rows of 8 ----------------
__global__ __launch_bounds__(256)
void k_lsm(const float* __restrict__ out2, float* __restrict__ out) {
  int n = blockIdx.x * blockDim.x + threadIdx.x;
  if (n >= NNODE) return;
  const float* r = out2 + (size_t)n * 8;
  float mx = r[0];
#pragma unroll
  for (int j = 1; j < 8; ++j) mx = fmaxf(mx, r[j]);
  float s = 0.f;
#pragma unroll
  for (int j = 0; j < 8; ++j) s += __expf(r[j] - mx);
  float ls = __logf(s) + mx;
#pragma unroll
  for (int j = 0; j < 8; ++j) out[(size_t)n * 8 + j] = r[j] - ls;
}

// ---------------- L1 scalar ----------------
__global__ __launch_bounds__(256)
void k_l1(const float* __restrict__ wfus1, const float* __restrict__ wfus2,
          float* __restrict__ o) {
  __shared__ float red[256];
  int tid = threadIdx.x;
  float s1 = 0.f, s2 = 0.f;
  for (int i = tid; i < 64 * 128; i += 256) s1 += fabsf(wfus1[i]);
  if (tid < 128) s2 = fabsf(wfus2[tid]);
  red[tid] = s1 / 8192.f + s2 / 128.f;
  __syncthreads();
  for (int off = 128; off; off >>= 1) {
    if (tid < off) red[tid] += red[tid + off];
    __syncthreads();
  }
  if (tid == 0) o[0] = red[0];
}

extern "C" void kernel_launch(void* const* d_in, const int* in_sizes, int n_in,
                              void* d_out, int out_size, void* d_ws, size_t ws_size,
                              hipStream_t stream) {
  const float* x = (const float*)d_in[0];
  const int* adj = (const int*)d_in[1];
  const float* W1 = (const float*)d_in[2];
  const float* a1 = (const float*)d_in[3];
  const float* W2 = (const float*)d_in[4];
  const float* a2 = (const float*)d_in[5];
  const float* wint1 = (const float*)d_in[6];
  const float* bint1 = (const float*)d_in[7];
  const float* wfus1 = (const float*)d_in[8];
  const float* bfus1 = (const float*)d_in[9];
  const float* wint2 = (const float*)d_in[10];
  const float* bint2 = (const float*)d_in[11];
  const float* wfus2 = (const float*)d_in[12];
  const float* bfus2 = (const float*)d_in[13];
  float* out = (float*)d_out;

  // workspace layout (floats), total 5,868,000 floats = 23.5 MB
  unsigned long long* bm = (unsigned long long*)d_ws;     // 2*3000*47 ull
  float* W = (float*)d_ws;
  float* Wh1 = W + 564000;    // [8][3000][64]
  float* f1b = W + 2100000;   // [8][3000]
  float* f2b = W + 2124000;   // [8][3000]
  float* h1cat = W + 2148000; // [2][3000][256]
  float* t1 = W + 3684000;    // [3000][128]
  float* out1 = W + 4068000;  // [3000][64]
  float* Wh2 = W + 4260000;   // [8][3000][32]
  float* h2cat = W + 5028000; // [2][3000][128]
  float* t2 = W + 5796000;    // [3000][16]
  float* out2 = W + 5844000;  // [3000][8]

  // adj -> bitmask
  k_bitmask<<<dim3((2 * NNODE + 3) / 4), 256, 0, stream>>>(adj, bm);

  // Wh1 = x @ W1 per (a,h)
  k_gemm<32, 64, 32, 2, 4, false, 0><<<dim3(94, 1, 8), 256, 0, stream>>>(
      x, 0, 512, W1, 512 * 64, nullptr, Wh1, (long long)NNODE * 64, 64, NNODE, 64, 512);

  // f1/f2 stage 1
  k_f12<<<dim3(6000), 256, 0, stream>>>(Wh1, a1, f1b, f2b, 64);
  // fused PV stage 1 -> h1cat (O-split 2)
  k_pvf<64, 32, 2><<<dim3(47, 2, 8), 256, 0, stream>>>(Wh1, f1b, f2b, bm, h1cat);

  // int1: t1[n][a*64+g] = elu(h1cat @ wint1^T + bint1)
  k_gemm<32, 64, 32, 2, 4, true, 1><<<dim3(94, 1, 2), 256, 0, stream>>>(
      h1cat, (long long)NNODE * 256, 256, wint1, 0, bint1, t1, 64, 128, NNODE, 64, 256);
  // fus1: out1 = t1 @ wfus1^T + bfus1
  k_gemm<32, 64, 32, 2, 4, true, 0><<<dim3(94, 1, 1), 256, 0, stream>>>(
      t1, 0, 128, wfus1, 0, bfus1, out1, 0, 64, NNODE, 64, 128);

  // Wh2 = out1 @ W2 per (a,h)
  k_gemm<32, 32, 32, 2, 2, false, 0><<<dim3(94, 1, 8), 256, 0, stream>>>(
      out1, 0, 64, W2, 64 * 32, nullptr, Wh2, (long long)NNODE * 32, 32, NNODE, 32, 64);

  // f1/f2 stage 2
  k_f12<<<dim3(6000), 256, 0, stream>>>(Wh2, a2, f1b, f2b, 32);
  // fused PV stage 2 -> h2cat (O-split 2)
  k_pvf<32, 16, 1><<<dim3(47, 2, 8), 256, 0, stream>>>(Wh2, f1b, f2b, bm, h2cat);

  // int2: t2[n][a*8+c] = elu(h2cat @ wint2^T + bint2)
  k_gemm<32, 8, 32, 2, 1, true, 1><<<dim3(94, 1, 2), 128, 0, stream>>>(
      h2cat, (long long)NNODE * 128, 128, wint2, 0, bint2, t2, 8, 16, NNODE, 8, 128);
  // fus2: out2 = t2 @ wfus2^T + bfus2
  k_gemm<32, 8, 16, 2, 1, true, 0><<<dim3(94, 1, 1), 128, 0, stream>>>(
      t2, 0, 16, wfus2, 0, bfus2, out2, 0, 8, NNODE, 8, 16);

  // log_softmax -> out[0..23999]
  k_lsm<<<dim3((NNODE + 255) / 256), 256, 0, stream>>>(out2, out);
  // l1 scalar -> out[24000]
  k_l1<<<dim3(1), 256, 0, stream>>>(wfus1, wfus2, out + 24000);
}

// Round 4
// 361.968 us; speedup vs baseline: 3.7735x; 1.8823x over previous
//
#include <hip/hip_runtime.h>
#include <hip/hip_bf16.h>
#include <math.h>

#define NNODE 3000
#define NCHUNK 47  // ceil(3000/64)
#define ALPHA 0.2f
#define LDT 3008   // padded m-stride of WhT (bf16), 16B-aligned rows

typedef __attribute__((ext_vector_type(8))) short short8v;   // 8 bf16 (4 VGPR)
typedef __attribute__((ext_vector_type(4))) float float4v;   // MFMA C/D

static __device__ __forceinline__ short f2b(float x) {
  __hip_bfloat16 b = __float2bfloat16(x);
  return *reinterpret_cast<short*>(&b);
}

// ---------------- adj -> bitmask ----------------
__global__ __launch_bounds__(256)
void k_bitmask(const int* __restrict__ adj, unsigned long long* __restrict__ bm) {
  int row = blockIdx.x * 4 + (threadIdx.x >> 6);
  int lane = threadIdx.x & 63;
  if (row >= 2 * NNODE) return;
  const int* arow = adj + (size_t)row * NNODE;
  unsigned long long* brow = bm + (size_t)row * NCHUNK;
  for (int c = 0; c < NCHUNK; ++c) {
    int m = c * 64 + lane;
    int v = (m < NNODE) ? (arow[m] > 0) : 0;
    unsigned long long mask = __ballot(v);
    if (lane == 0) brow[c] = mask;
  }
}

// ---------------- generic tiled fp32 GEMM ----------------
template <int BM, int BN, int BK, int TM, int TN, bool BT, int ACT>
__global__ __launch_bounds__((BM / TM) * (BN / TN))
void k_gemm(const float* __restrict__ A, long long boffA, int ldA,
            const float* __restrict__ B, long long boffB,
            const float* __restrict__ bias,
            float* __restrict__ C, long long boffC, int ldC,
            int M, int N, int K) {
  constexpr int NT = (BM / TM) * (BN / TN);
  constexpr int NCG = BN / TN;
  const int z = blockIdx.z;
  A += boffA * z;
  B += boffB * z;
  C += boffC * z;
  const int m0 = blockIdx.x * BM;
  const int n0 = blockIdx.y * BN;
  __shared__ float As[BK][BM + 4];
  __shared__ float Bs[BK][BN + 4];
  const int tid = threadIdx.x;
  const int trow = tid / NCG, tcol = tid % NCG;
  float acc[TM][TN] = {};
  for (int k0 = 0; k0 < K; k0 += BK) {
    for (int i = tid; i < BM * BK; i += NT) {
      int r = i / BK, c = i % BK;
      int gm = m0 + r;
      As[c][r] = (gm < M) ? A[(size_t)gm * ldA + (k0 + c)] : 0.f;
    }
    if (!BT) {
      for (int i = tid; i < BK * BN; i += NT) {
        int r = i / BN, c = i % BN;
        Bs[r][c] = B[(size_t)(k0 + r) * N + (n0 + c)];
      }
    } else {
      for (int i = tid; i < BK * BN; i += NT) {
        int r = i % BK, c = i / BK;
        Bs[r][c] = B[(size_t)(n0 + c) * K + (k0 + r)];
      }
    }
    __syncthreads();
#pragma unroll 8
    for (int kk = 0; kk < BK; ++kk) {
      float ar[TM], br[TN];
#pragma unroll
      for (int i2 = 0; i2 < TM; ++i2) ar[i2] = As[kk][trow * TM + i2];
#pragma unroll
      for (int j = 0; j < TN; ++j) br[j] = Bs[kk][tcol * TN + j];
#pragma unroll
      for (int i2 = 0; i2 < TM; ++i2)
#pragma unroll
        for (int j = 0; j < TN; ++j)
          acc[i2][j] = fmaf(ar[i2], br[j], acc[i2][j]);
    }
    __syncthreads();
  }
#pragma unroll
  for (int i2 = 0; i2 < TM; ++i2) {
    int gm = m0 + trow * TM + i2;
    if (gm >= M) continue;
#pragma unroll
    for (int j = 0; j < TN; ++j) {
      int gn = n0 + tcol * TN + j;
      float v = acc[i2][j];
      if (bias) v += bias[gn];
      if (ACT == 1) v = v > 0.f ? v : (__expf(v) - 1.f);
      C[(size_t)gm * ldC + gn] = v;
    }
  }
}

// ---------------- f1/f2 = Wh . a ----------------
__global__ __launch_bounds__(256)
void k_f12(const float* __restrict__ Wh, const float* __restrict__ avec,
           float* __restrict__ f1, float* __restrict__ f2, int O) {
  int row = blockIdx.x * 4 + (threadIdx.x >> 6);
  int lane = threadIdx.x & 63;
  if (row >= 8 * NNODE) return;
  int z = row / NNODE;
  const float* w = Wh + (size_t)row * O;
  const float* av = avec + (size_t)z * 2 * O;
  float s1 = 0.f, s2 = 0.f;
  for (int o = lane; o < O; o += 64) {
    float v = w[o];
    s1 += v * av[o];
    s2 += v * av[O + o];
  }
  for (int off = 32; off; off >>= 1) {
    s1 += __shfl_down(s1, off);
    s2 += __shfl_down(s2, off);
  }
  if (lane == 0) {
    f1[row] = s1;
    f2[row] = s2;
  }
}

// ---------------- Wh [z][m][O] fp32 -> WhT [z][O][LDT] bf16 ----------------
template <int O>
__global__ __launch_bounds__(256)
void k_wht(const float* __restrict__ Wh, unsigned short* __restrict__ WhT) {
  const int z = blockIdx.y;
  const int m0 = blockIdx.x * 64;
  const float* W = Wh + (size_t)z * NNODE * O;
  unsigned short* T = WhT + (size_t)z * O * LDT;
  __shared__ float Lw[64][O + 4];
  const int tid = threadIdx.x;
  // load 64 x O tile, coalesced float4
  for (int idx = tid; idx < 64 * (O / 4); idx += 256) {
    int m = idx / (O / 4), oc = idx % (O / 4);
    float4 v = make_float4(0.f, 0.f, 0.f, 0.f);
    if (m0 + m < NNODE)
      v = *reinterpret_cast<const float4*>(&W[(size_t)(m0 + m) * O + 4 * oc]);
    *reinterpret_cast<float4*>(&Lw[m][4 * oc]) = v;
  }
  __syncthreads();
  // write transposed bf16: thread -> (o = tid & (O-1), mc chunks of 8 m)
  const int o = tid & (O - 1);
  for (int mc = tid / O; mc < 8; mc += 256 / O) {
    short8v w;
#pragma unroll
    for (int j = 0; j < 8; ++j) w[j] = f2b(Lw[8 * mc + j][o]);
    *reinterpret_cast<short8v*>(&T[(size_t)o * LDT + m0 + 8 * mc]) = w;
  }
}

// ---------------- MFMA fused PV ----------------
// Block: 64 rows (4 waves x 16) x OW cols, full K sweep.
// A (P) generated in registers; B (WhT) staged in swizzled LDS.
template <int O, int OW>
__global__ __launch_bounds__(256)
void k_pvm(const unsigned short* __restrict__ WhT,
           const float* __restrict__ f1, const float* __restrict__ f2,
           const unsigned long long* __restrict__ bm,
           float* __restrict__ Cc) {
  constexpr int HO = 4 * O;
  constexpr int NCT = OW / 16;
  const int z = blockIdx.z, a = z >> 2, h = z & 3;
  const int ocol0 = blockIdx.y * OW;
  const int n0 = blockIdx.x * 64;
  const int tid = threadIdx.x;
  const int l = tid & 63;
  const int r0 = 16 * (tid >> 6);  // wave's row base
  const int li = l & 15, g = l >> 4;
  const unsigned short* WT = WhT + (size_t)z * O * LDT;
  const float* f2B = f2 + (size_t)z * NNODE;
  const unsigned long long* bmA = bm + (size_t)a * NNODE * NCHUNK;
  __shared__ __align__(16) unsigned short Whs[OW * 64];  // swizzled [o][k] bf16
  __shared__ float F2s[64];
  __shared__ float F1s[64];
  __shared__ unsigned long long Bw[64];
  if (tid < 64) {
    int n = n0 + tid;
    F1s[tid] = (n < NNODE) ? f1[(size_t)z * NNODE + n] : 0.f;
  }
  float4v acc[NCT];
#pragma unroll
  for (int ct = 0; ct < NCT; ++ct) acc[ct] = {0.f, 0.f, 0.f, 0.f};
  float rs = 0.f;
  for (int k0 = 0; k0 < NNODE; k0 += 64) {
    // ---- stage Bw, F2s, Whs tile ----
    if (tid < 64) {
      int n = n0 + tid;
      Bw[tid] = (n < NNODE) ? bmA[(size_t)n * NCHUNK + (k0 >> 6)] : 0ULL;
      int m = k0 + tid;
      F2s[tid] = (m < NNODE) ? f2B[m] : 0.f;
    }
    {
      int orow = tid >> 3;   // 0..31 (OW==32)
      int c8 = tid & 7;      // 8-bf16 chunk
      uint4 v = *reinterpret_cast<const uint4*>(
          WT + (size_t)(ocol0 + orow) * LDT + k0 + 8 * c8);
      int boff = (orow * 128 + c8 * 16) ^ ((orow & 7) << 4);
      *reinterpret_cast<uint4*>(reinterpret_cast<char*>(Whs) + boff) = v;
    }
    __syncthreads();
    // ---- generate A-frags (P) in registers ----
    const unsigned long long bwr = Bw[r0 + li];
    const float f1v = F1s[r0 + li];
    short8v afr[2];
#pragma unroll
    for (int q = 0; q < 2; ++q) {
      int koff = 32 * q + 8 * g;
      unsigned bits = (unsigned)(bwr >> koff) & 0xffu;
      const float4 fa = *reinterpret_cast<const float4*>(&F2s[koff]);
      const float4 fb = *reinterpret_cast<const float4*>(&F2s[koff + 4]);
      float f2v[8] = {fa.x, fa.y, fa.z, fa.w, fb.x, fb.y, fb.z, fb.w};
#pragma unroll
      for (int e = 0; e < 8; ++e) {
        float t = f1v + f2v[e];
        t = fmaxf(t, ALPHA * t);          // leaky relu
        float p = __expf(t);
        p = (bits & (1u << e)) ? p : 0.f; // mask
        rs += p;
        afr[q][e] = f2b(p);
      }
    }
    // ---- B-frags + MFMA ----
#pragma unroll
    for (int ct = 0; ct < NCT; ++ct) {
      int orow = ct * 16 + li;
#pragma unroll
      for (int q = 0; q < 2; ++q) {
        int boff = (orow * 128 + q * 64 + 16 * g) ^ ((li & 7) << 4);
        short8v bfr = *reinterpret_cast<const short8v*>(
            reinterpret_cast<const char*>(Whs) + boff);
        acc[ct] = __builtin_amdgcn_mfma_f32_16x16x32_bf16(afr[q], bfr, acc[ct], 0, 0, 0);
      }
    }
    __syncthreads();
  }
  // ---- rowsum reduce (rows live at lane li across g groups) ----
  rs += __shfl_xor(rs, 16);
  rs += __shfl_xor(rs, 32);
  // ---- epilogue: normalize, ELU, head-concat scatter ----
#pragma unroll
  for (int j = 0; j < 4; ++j) {
    int rloc = 4 * g + j;                 // C/D: row = 4*(l>>4)+reg
    float s = __shfl(rs, rloc);
    float inv = (s > 0.f) ? 1.f / s : 0.f;
    int n = n0 + r0 + rloc;
    if (n < NNODE) {
#pragma unroll
      for (int ct = 0; ct < NCT; ++ct) {
        float v = acc[ct][j] * inv;
        v = v > 0.f ? v : (__expf(v) - 1.f);
        Cc[((size_t)a * NNODE + n) * HO + h * O + ocol0 + ct * 16 + li] = v;
      }
    }
  }
}

// ---------------- log_softmax rows of 8 ----------------
__global__ __launch_bounds__(256)
void k_lsm(const float* __restrict__ out2, float* __restrict__ out) {
  int n = blockIdx.x * blockDim.x + threadIdx.x;
  if (n >= NNODE) return;
  const float* r = out2 + (size_t)n * 8;
  float mx = r[0];
#pragma unroll
  for (int j = 1; j < 8; ++j) mx = fmaxf(mx, r[j]);
  float s = 0.f;
#pragma unroll
  for (int j = 0; j < 8; ++j) s += __expf(r[j] - mx);
  float ls = __logf(s) + mx;
#pragma unroll
  for (int j = 0; j < 8; ++j) out[(size_t)n * 8 + j] = r[j] - ls;
}

// ---------------- L1 scalar ----------------
__global__ __launch_bounds__(256)
void k_l1(const float* __restrict__ wfus1, const float* __restrict__ wfus2,
          float* __restrict__ o) {
  __shared__ float red[256];
  int tid = threadIdx.x;
  float s1 = 0.f, s2 = 0.f;
  for (int i = tid; i < 64 * 128; i += 256) s1 += fabsf(wfus1[i]);
  if (tid < 128) s2 = fabsf(wfus2[tid]);
  red[tid] = s1 / 8192.f + s2 / 128.f;
  __syncthreads();
  for (int off = 128; off; off >>= 1) {
    if (tid < off) red[tid] += red[tid + off];
    __syncthreads();
  }
  if (tid == 0) o[0] = red[0];
}

extern "C" void kernel_launch(void* const* d_in, const int* in_sizes, int n_in,
                              void* d_out, int out_size, void* d_ws, size_t ws_size,
                              hipStream_t stream) {
  const float* x = (const float*)d_in[0];
  const int* adj = (const int*)d_in[1];
  const float* W1 = (const float*)d_in[2];
  const float* a1 = (const float*)d_in[3];
  const float* W2 = (const float*)d_in[4];
  const float* a2 = (const float*)d_in[5];
  const float* wint1 = (const float*)d_in[6];
  const float* bint1 = (const float*)d_in[7];
  const float* wfus1 = (const float*)d_in[8];
  const float* bfus1 = (const float*)d_in[9];
  const float* wint2 = (const float*)d_in[10];
  const float* bint2 = (const float*)d_in[11];
  const float* wfus2 = (const float*)d_in[12];
  const float* bfus2 = (const float*)d_in[13];
  float* out = (float*)d_out;

  // workspace layout (floats), total 5,868,000 floats = 23.47 MB
  unsigned long long* bm = (unsigned long long*)d_ws;  // [2][3000][47]
  float* W = (float*)d_ws;
  float* Wh1 = W + 564000;    // [8][3000][64]
  float* f1b = W + 2100000;   // [8][3000]
  float* f2b = W + 2124000;   // [8][3000]
  float* h1cat = W + 2148000; // [2][3000][256]
  float* t1 = W + 3684000;    // [3000][128]
  float* out1 = W + 4068000;  // [3000][64]
  float* Wh2 = W + 4260000;   // [8][3000][32]
  float* h2cat = W + 5028000; // [2][3000][128]
  float* t2 = W + 5796000;    // [3000][16]
  float* out2 = W + 5844000;  // [3000][8]
  // WhT1 [8][64][3008] bf16 = 770,048 floats: aliases t1/out1/Wh2-head (dead then)
  unsigned short* WhT1 = (unsigned short*)(W + 3684000);
  // WhT2 [8][32][3008] bf16 = 385,024 floats: aliases Wh1 (dead then)
  unsigned short* WhT2 = (unsigned short*)(W + 564000);

  // adj -> bitmask
  k_bitmask<<<dim3((2 * NNODE + 3) / 4), 256, 0, stream>>>(adj, bm);

  // Wh1 = x @ W1 per (a,h)
  k_gemm<32, 64, 32, 2, 4, false, 0><<<dim3(94, 1, 8), 256, 0, stream>>>(
      x, 0, 512, W1, 512 * 64, nullptr, Wh1, (long long)NNODE * 64, 64, NNODE, 64, 512);

  // f1/f2 stage 1 + WhT1
  k_f12<<<dim3(6000), 256, 0, stream>>>(Wh1, a1, f1b, f2b, 64);
  k_wht<64><<<dim3(47, 8), 256, 0, stream>>>(Wh1, WhT1);
  // MFMA fused PV stage 1 -> h1cat (col-split 2)
  k_pvm<64, 32><<<dim3(47, 2, 8), 256, 0, stream>>>(WhT1, f1b, f2b, bm, h1cat);

  // int1: t1[n][a*64+g] = elu(h1cat @ wint1^T + bint1)   (overwrites WhT1 - ok)
  k_gemm<32, 64, 32, 2, 4, true, 1><<<dim3(94, 1, 2), 256, 0, stream>>>(
      h1cat, (long long)NNODE * 256, 256, wint1, 0, bint1, t1, 64, 128, NNODE, 64, 256);
  // fus1: out1 = t1 @ wfus1^T + bfus1
  k_gemm<32, 64, 32, 2, 4, true, 0><<<dim3(94, 1, 1), 256, 0, stream>>>(
      t1, 0, 128, wfus1, 0, bfus1, out1, 0, 64, NNODE, 64, 128);

  // Wh2 = out1 @ W2 per (a,h)
  k_gemm<32, 32, 32, 2, 2, false, 0><<<dim3(94, 1, 8), 256, 0, stream>>>(
      out1, 0, 64, W2, 64 * 32, nullptr, Wh2, (long long)NNODE * 32, 32, NNODE, 32, 64);

  // f1/f2 stage 2 + WhT2
  k_f12<<<dim3(6000), 256, 0, stream>>>(Wh2, a2, f1b, f2b, 32);
  k_wht<32><<<dim3(47, 8), 256, 0, stream>>>(Wh2, WhT2);
  // MFMA fused PV stage 2 -> h2cat
  k_pvm<32, 32><<<dim3(47, 1, 8), 256, 0, stream>>>(WhT2, f1b, f2b, bm, h2cat);

  // int2: t2[n][a*8+c] = elu(h2cat @ wint2^T + bint2)
  k_gemm<32, 8, 32, 2, 1, true, 1><<<dim3(94, 1, 2), 128, 0, stream>>>(
      h2cat, (long long)NNODE * 128, 128, wint2, 0, bint2, t2, 8, 16, NNODE, 8, 128);
  // fus2: out2 = t2 @ wfus2^T + bfus2
  k_gemm<32, 8, 16, 2, 1, true, 0><<<dim3(94, 1, 1), 128, 0, stream>>>(
      t2, 0, 16, wfus2, 0, bfus2, out2, 0, 8, NNODE, 8, 16);

  // log_softmax -> out[0..23999]
  k_lsm<<<dim3((NNODE + 255) / 256), 256, 0, stream>>>(out2, out);
  // l1 scalar -> out[24000]
  k_l1<<<dim3(1), 256, 0, stream>>>(wfus1, wfus2, out + 24000);
}

// Round 5
// 275.469 us; speedup vs baseline: 4.9584x; 1.3140x over previous
//
#include <hip/hip_runtime.h>
#include <hip/hip_bf16.h>
#include <math.h>

#define NNODE 3000
#define NCHUNK 47  // ceil(3000/64)
#define ALPHA 0.2f
#define LDT 3008   // padded m-stride of WhT (bf16)

typedef __attribute__((ext_vector_type(8))) short short8v;
typedef __attribute__((ext_vector_type(4))) short short4v;
typedef __attribute__((ext_vector_type(4))) float float4v;

static __device__ __forceinline__ short f2b(float x) {
  __hip_bfloat16 b = __float2bfloat16(x);
  return *reinterpret_cast<short*>(&b);
}

// ---------------- adj -> bitmask ----------------
__global__ __launch_bounds__(256)
void k_bitmask(const int* __restrict__ adj, unsigned long long* __restrict__ bm) {
  int row = blockIdx.x * 4 + (threadIdx.x >> 6);
  int lane = threadIdx.x & 63;
  if (row >= 2 * NNODE) return;
  const int* arow = adj + (size_t)row * NNODE;
  unsigned long long* brow = bm + (size_t)row * NCHUNK;
  for (int c = 0; c < NCHUNK; ++c) {
    int m = c * 64 + lane;
    int v = (m < NNODE) ? (arow[m] > 0) : 0;
    unsigned long long mask = __ballot(v);
    if (lane == 0) brow[c] = mask;
  }
}

// ---------------- fp32 -> bf16 cast (8 elems/thread) ----------------
__global__ __launch_bounds__(256)
void k_cast(const float* __restrict__ src, unsigned short* __restrict__ dst,
            int count8) {
  int i = blockIdx.x * 256 + threadIdx.x;
  if (i >= count8) return;
  float4 va = reinterpret_cast<const float4*>(src)[2 * i];
  float4 vb = reinterpret_cast<const float4*>(src)[2 * i + 1];
  short8v w;
  w[0] = f2b(va.x); w[1] = f2b(va.y); w[2] = f2b(va.z); w[3] = f2b(va.w);
  w[4] = f2b(vb.x); w[5] = f2b(vb.y); w[6] = f2b(vb.z); w[7] = f2b(vb.w);
  reinterpret_cast<short8v*>(dst)[i] = w;
}

// ------- weight transpose+cast: src [z][rows][O] f32 -> dst [z][O][ldT] bf16 -------
template <int O>
__global__ __launch_bounds__(256)
void k_wt(const float* __restrict__ src, unsigned short* __restrict__ dst,
          int rows, int ldT) {
  const int z = blockIdx.y;
  const int m0 = blockIdx.x * 64;
  src += (size_t)z * rows * O;
  dst += (size_t)z * O * ldT;
  __shared__ float Lw[64][O + 4];
  const int tid = threadIdx.x;
  for (int idx = tid; idx < 64 * (O / 4); idx += 256) {
    int m = idx / (O / 4), oc = idx % (O / 4);
    float4 v = make_float4(0.f, 0.f, 0.f, 0.f);
    if (m0 + m < rows)
      v = *reinterpret_cast<const float4*>(&src[(size_t)(m0 + m) * O + 4 * oc]);
    *reinterpret_cast<float4*>(&Lw[m][4 * oc]) = v;
  }
  __syncthreads();
  const int o = tid & (O - 1);
  for (int mc = tid / O; mc < 8; mc += 256 / O) {
    short8v w;
#pragma unroll
    for (int j = 0; j < 8; ++j) w[j] = f2b(Lw[8 * mc + j][o]);
    *reinterpret_cast<short8v*>(&dst[(size_t)o * ldT + m0 + 8 * mc]) = w;
  }
}

// ---------------- bf16 MFMA GEMM, 32 rows x OW cols per 128-thr block ----------------
// A [..][KC] bf16 row-major; B [O][KC] bf16 (pre-transposed). MODE 1=ATT: epilogue
// computes f1/f2 = acc . a-vec and writes WhT bf16 transposed. MODE 0=LIN: bias
// (+optional ELU) and bf16 C write.
template <int OW, int KC, int MODE, int ACT>
__global__ __launch_bounds__(128)
void k_xw(const unsigned short* __restrict__ Ab, long long boffA,
          const unsigned short* __restrict__ Bb, long long boffB,
          const float* __restrict__ aux,            // ATT: a-vec [z][2*OW]; LIN: bias
          unsigned short* __restrict__ Wo,          // ATT: WhT; LIN: Cb bf16
          long long boffW,
          float* __restrict__ f1o, float* __restrict__ f2o,
          int colStrideZ, int ldC) {
  constexpr int NCT = OW / 16;
  const int z = blockIdx.z;
  const int n0 = blockIdx.x * 32;
  const int ocol0 = blockIdx.y * OW;
  const unsigned short* A = Ab + boffA * z;
  const unsigned short* B = Bb + boffB * z;
  const int tid = threadIdx.x;
  const int l = tid & 63, g = l >> 4, li = l & 15;
  const int r0 = 16 * (tid >> 6);  // 0 or 16
  __shared__ __align__(16) unsigned short As[32 * 64];
  __shared__ __align__(16) unsigned short Bs[OW * 64];
  float4v acc[NCT];
#pragma unroll
  for (int ct = 0; ct < NCT; ++ct) acc[ct] = {0.f, 0.f, 0.f, 0.f};
  for (int k0 = 0; k0 < KC; k0 += 64) {
    for (int i = tid; i < 256; i += 128) {
      int r = i >> 3, c8 = i & 7;
      uint4 v = {0u, 0u, 0u, 0u};
      if (n0 + r < NNODE)
        v = *reinterpret_cast<const uint4*>(A + (size_t)(n0 + r) * KC + k0 + 8 * c8);
      int boff = (r * 128 + c8 * 16) ^ ((r & 7) << 4);
      *reinterpret_cast<uint4*>(reinterpret_cast<char*>(As) + boff) = v;
    }
    for (int i = tid; i < OW * 8; i += 128) {
      int ro = i >> 3, c8 = i & 7;
      uint4 v = *reinterpret_cast<const uint4*>(B + (size_t)(ocol0 + ro) * KC + k0 + 8 * c8);
      int boff = (ro * 128 + c8 * 16) ^ ((ro & 7) << 4);
      *reinterpret_cast<uint4*>(reinterpret_cast<char*>(Bs) + boff) = v;
    }
    __syncthreads();
#pragma unroll
    for (int q = 0; q < 2; ++q) {
      int aoff = ((r0 + li) * 128 + q * 64 + 16 * g) ^ ((li & 7) << 4);
      short8v afr = *reinterpret_cast<const short8v*>(
          reinterpret_cast<const char*>(As) + aoff);
#pragma unroll
      for (int ct = 0; ct < NCT; ++ct) {
        int orow = ct * 16 + li;
        int boff = (orow * 128 + q * 64 + 16 * g) ^ ((li & 7) << 4);
        short8v bfr = *reinterpret_cast<const short8v*>(
            reinterpret_cast<const char*>(Bs) + boff);
        acc[ct] = __builtin_amdgcn_mfma_f32_16x16x32_bf16(afr, bfr, acc[ct], 0, 0, 0);
      }
    }
    __syncthreads();
  }
  if (MODE == 1) {
    // f1/f2 = acc . a-vec, reduced over the 16 col-lanes
    const float* av = aux + (size_t)z * 2 * OW;
    float p1[4] = {0.f, 0.f, 0.f, 0.f}, p2[4] = {0.f, 0.f, 0.f, 0.f};
#pragma unroll
    for (int ct = 0; ct < NCT; ++ct) {
      float a1v = av[ct * 16 + li];
      float a2v = av[OW + ct * 16 + li];
#pragma unroll
      for (int j = 0; j < 4; ++j) {
        p1[j] += acc[ct][j] * a1v;
        p2[j] += acc[ct][j] * a2v;
      }
    }
#pragma unroll
    for (int off = 1; off < 16; off <<= 1) {
#pragma unroll
      for (int j = 0; j < 4; ++j) {
        p1[j] += __shfl_xor(p1[j], off);
        p2[j] += __shfl_xor(p2[j], off);
      }
    }
    // WhT transposed write: lane owns col (ct*16+li), rows n0+r0+4g..+3
    unsigned short* WT = Wo + boffW * z;
#pragma unroll
    for (int ct = 0; ct < NCT; ++ct) {
      short4v w;
#pragma unroll
      for (int j = 0; j < 4; ++j) w[j] = f2b(acc[ct][j]);
      *reinterpret_cast<short4v*>(
          &WT[(size_t)(ocol0 + ct * 16 + li) * LDT + n0 + r0 + 4 * g]) = w;
    }
    if (li == 0) {
#pragma unroll
      for (int j = 0; j < 4; ++j) {
        int n = n0 + r0 + 4 * g + j;
        if (n < NNODE) {
          f1o[(size_t)z * NNODE + n] = p1[j];
          f2o[(size_t)z * NNODE + n] = p2[j];
        }
      }
    }
  } else {
#pragma unroll
    for (int ct = 0; ct < NCT; ++ct) {
      float b = aux[ocol0 + ct * 16 + li];
#pragma unroll
      for (int j = 0; j < 4; ++j) {
        int n = n0 + r0 + 4 * g + j;
        if (n < NNODE) {
          float v = acc[ct][j] + b;
          if (ACT == 1) v = v > 0.f ? v : (__expf(v) - 1.f);
          Wo[(size_t)n * ldC + z * colStrideZ + ocol0 + ct * 16 + li] = (unsigned short)f2b(v);
        }
      }
    }
  }
}

// ---------------- MFMA fused PV (32 rows, OW cols, 128 threads) ----------------
template <int O, int OW, bool WB16>
__global__ __launch_bounds__(128)
void k_pvm(const unsigned short* __restrict__ WhT,
           const float* __restrict__ f1, const float* __restrict__ f2,
           const unsigned long long* __restrict__ bm,
           float* __restrict__ Cf, unsigned short* __restrict__ Cb) {
  constexpr int HO = 4 * O;
  constexpr int NCT = OW / 16;
  const int z = blockIdx.z, a = z >> 2, h = z & 3;
  const int ocol0 = blockIdx.y * OW;
  const int n0 = blockIdx.x * 32;
  const int tid = threadIdx.x;
  const int l = tid & 63;
  const int r0 = 16 * (tid >> 6);  // 0 or 16
  const int li = l & 15, g = l >> 4;
  const unsigned short* WT = WhT + (size_t)z * O * LDT;
  const float* f2B = f2 + (size_t)z * NNODE;
  const unsigned long long* bmA = bm + (size_t)a * NNODE * NCHUNK;
  __shared__ __align__(16) unsigned short Whs[OW * 64];
  __shared__ float F2s[64];
  __shared__ float F1s[32];
  __shared__ unsigned long long Bw[32];
  if (tid < 32) {
    int n = n0 + tid;
    F1s[tid] = (n < NNODE) ? f1[(size_t)z * NNODE + n] : 0.f;
  }
  float4v acc[NCT];
#pragma unroll
  for (int ct = 0; ct < NCT; ++ct) acc[ct] = {0.f, 0.f, 0.f, 0.f};
  float rs = 0.f;
  for (int k0 = 0; k0 < NNODE; k0 += 64) {
    if (tid < 32) {
      int n = n0 + tid;
      Bw[tid] = (n < NNODE) ? bmA[(size_t)n * NCHUNK + (k0 >> 6)] : 0ULL;
    } else if (tid < 96) {
      int t = tid - 32;
      int m = k0 + t;
      F2s[t] = (m < NNODE) ? f2B[m] : 0.f;
    }
    for (int i = tid; i < OW * 8; i += 128) {
      int orow = i >> 3, c8 = i & 7;
      uint4 v = *reinterpret_cast<const uint4*>(
          WT + (size_t)(ocol0 + orow) * LDT + k0 + 8 * c8);
      int boff = (orow * 128 + c8 * 16) ^ ((orow & 7) << 4);
      *reinterpret_cast<uint4*>(reinterpret_cast<char*>(Whs) + boff) = v;
    }
    __syncthreads();
    // generate P A-frags in registers
    const unsigned long long bwr = Bw[r0 + li];
    const float f1v = F1s[r0 + li];
    short8v afr[2];
#pragma unroll
    for (int q = 0; q < 2; ++q) {
      int koff = 32 * q + 8 * g;
      unsigned bits = (unsigned)(bwr >> koff) & 0xffu;
      const float4 fa = *reinterpret_cast<const float4*>(&F2s[koff]);
      const float4 fb = *reinterpret_cast<const float4*>(&F2s[koff + 4]);
      float f2v[8] = {fa.x, fa.y, fa.z, fa.w, fb.x, fb.y, fb.z, fb.w};
#pragma unroll
      for (int e = 0; e < 8; ++e) {
        float t = f1v + f2v[e];
        t = fmaxf(t, ALPHA * t);
        float p = __expf(t);
        p = (bits & (1u << e)) ? p : 0.f;
        rs += p;
        afr[q][e] = f2b(p);
      }
    }
#pragma unroll
    for (int ct = 0; ct < NCT; ++ct) {
      int orow = ct * 16 + li;
#pragma unroll
      for (int q = 0; q < 2; ++q) {
        int boff = (orow * 128 + q * 64 + 16 * g) ^ ((li & 7) << 4);
        short8v bfr = *reinterpret_cast<const short8v*>(
            reinterpret_cast<const char*>(Whs) + boff);
        acc[ct] = __builtin_amdgcn_mfma_f32_16x16x32_bf16(afr[q], bfr, acc[ct], 0, 0, 0);
      }
    }
    __syncthreads();
  }
  rs += __shfl_xor(rs, 16);
  rs += __shfl_xor(rs, 32);
#pragma unroll
  for (int j = 0; j < 4; ++j) {
    int rloc = 4 * g + j;
    float s = __shfl(rs, rloc);
    float inv = (s > 0.f) ? 1.f / s : 0.f;
    int n = n0 + r0 + rloc;
    if (n < NNODE) {
#pragma unroll
      for (int ct = 0; ct < NCT; ++ct) {
        float v = acc[ct][j] * inv;
        v = v > 0.f ? v : (__expf(v) - 1.f);
        size_t idx = ((size_t)a * NNODE + n) * HO + h * O + ocol0 + ct * 16 + li;
        if (WB16) Cb[idx] = (unsigned short)f2b(v);
        else Cf[idx] = v;
      }
    }
  }
}

// ---------------- generic tiled fp32 GEMM (tail layers) ----------------
template <int BM, int BN, int BK, int TM, int TN, bool BT, int ACT>
__global__ __launch_bounds__((BM / TM) * (BN / TN))
void k_gemm(const float* __restrict__ A, long long boffA, int ldA,
            const float* __restrict__ B, long long boffB,
            const float* __restrict__ bias,
            float* __restrict__ C, long long boffC, int ldC,
            int M, int N, int K) {
  constexpr int NT = (BM / TM) * (BN / TN);
  constexpr int NCG = BN / TN;
  const int z = blockIdx.z;
  A += boffA * z;
  B += boffB * z;
  C += boffC * z;
  const int m0 = blockIdx.x * BM;
  const int n0 = blockIdx.y * BN;
  __shared__ float As[BK][BM + 4];
  __shared__ float Bs[BK][BN + 4];
  const int tid = threadIdx.x;
  const int trow = tid / NCG, tcol = tid % NCG;
  float acc[TM][TN] = {};
  for (int k0 = 0; k0 < K; k0 += BK) {
    for (int i = tid; i < BM * BK; i += NT) {
      int r = i / BK, c = i % BK;
      int gm = m0 + r;
      As[c][r] = (gm < M) ? A[(size_t)gm * ldA + (k0 + c)] : 0.f;
    }
    if (!BT) {
      for (int i = tid; i < BK * BN; i += NT) {
        int r = i / BN, c = i % BN;
        Bs[r][c] = B[(size_t)(k0 + r) * N + (n0 + c)];
      }
    } else {
      for (int i = tid; i < BK * BN; i += NT) {
        int r = i % BK, c = i / BK;
        Bs[r][c] = B[(size_t)(n0 + c) * K + (k0 + r)];
      }
    }
    __syncthreads();
#pragma unroll 8
    for (int kk = 0; kk < BK; ++kk) {
      float ar[TM], br[TN];
#pragma unroll
      for (int i2 = 0; i2 < TM; ++i2) ar[i2] = As[kk][trow * TM + i2];
#pragma unroll
      for (int j = 0; j < TN; ++j) br[j] = Bs[kk][tcol * TN + j];
#pragma unroll
      for (int i2 = 0; i2 < TM; ++i2)
#pragma unroll
        for (int j = 0; j < TN; ++j)
          acc[i2][j] = fmaf(ar[i2], br[j], acc[i2][j]);
    }
    __syncthreads();
  }
#pragma unroll
  for (int i2 = 0; i2 < TM; ++i2) {
    int gm = m0 + trow * TM + i2;
    if (gm >= M) continue;
#pragma unroll
    for (int j = 0; j < TN; ++j) {
      int gn = n0 + tcol * TN + j;
      float v = acc[i2][j];
      if (bias) v += bias[gn];
      if (ACT == 1) v = v > 0.f ? v : (__expf(v) - 1.f);
      C[(size_t)gm * ldC + gn] = v;
    }
  }
}

// ---------------- log_softmax rows of 8 ----------------
__global__ __launch_bounds__(256)
void k_lsm(const float* __restrict__ out2, float* __restrict__ out) {
  int n = blockIdx.x * blockDim.x + threadIdx.x;
  if (n >= NNODE) return;
  const float* r = out2 + (size_t)n * 8;
  float mx = r[0];
#pragma unroll
  for (int j = 1; j < 8; ++j) mx = fmaxf(mx, r[j]);
  float s = 0.f;
#pragma unroll
  for (int j = 0; j < 8; ++j) s += __expf(r[j] - mx);
  float ls = __logf(s) + mx;
#pragma unroll
  for (int j = 0; j < 8; ++j) out[(size_t)n * 8 + j] = r[j] - ls;
}

// ---------------- L1 scalar ----------------
__global__ __launch_bounds__(256)
void k_l1(const float* __restrict__ wfus1, const float* __restrict__ wfus2,
          float* __restrict__ o) {
  __shared__ float red[256];
  int tid = threadIdx.x;
  float s1 = 0.f, s2 = 0.f;
  for (int i = tid; i < 64 * 128; i += 256) s1 += fabsf(wfus1[i]);
  if (tid < 128) s2 = fabsf(wfus2[tid]);
  red[tid] = s1 / 8192.f + s2 / 128.f;
  __syncthreads();
  for (int off = 128; off; off >>= 1) {
    if (tid < off) red[tid] += red[tid + off];
    __syncthreads();
  }
  if (tid == 0) o[0] = red[0];
}

extern "C" void kernel_launch(void* const* d_in, const int* in_sizes, int n_in,
                              void* d_out, int out_size, void* d_ws, size_t ws_size,
                              hipStream_t stream) {
  const float* x = (const float*)d_in[0];
  const int* adj = (const int*)d_in[1];
  const float* W1 = (const float*)d_in[2];
  const float* a1 = (const float*)d_in[3];
  const float* W2 = (const float*)d_in[4];
  const float* a2 = (const float*)d_in[5];
  const float* wint1 = (const float*)d_in[6];
  const float* bint1 = (const float*)d_in[7];
  const float* wfus1 = (const float*)d_in[8];
  const float* bfus1 = (const float*)d_in[9];
  const float* wint2 = (const float*)d_in[10];
  const float* bint2 = (const float*)d_in[11];
  const float* wfus2 = (const float*)d_in[12];
  const float* bfus2 = (const float*)d_in[13];
  float* out = (float*)d_out;

  // workspace (float offsets), max used 3,928,000 floats = 15.7 MB
  float* W = (float*)d_ws;
  unsigned long long* bm = (unsigned long long*)d_ws;            // [2][3000][47]
  unsigned short* xb = (unsigned short*)(W + 564000);            // [3000][512] bf16 (dead after xw1)
  unsigned short* out1b = (unsigned short*)(W + 564000);         // [3000][64] bf16 (after fus1)
  unsigned short* WhT2 = (unsigned short*)(W + 660000);          // [8][32][3008] bf16
  unsigned short* W1Tb = (unsigned short*)(W + 1332000);         // [8][64][512] bf16
  unsigned short* wint1b = (unsigned short*)(W + 1463072);       // [64][256] bf16
  unsigned short* wfus1b = (unsigned short*)(W + 1471264);       // [64][128] bf16
  unsigned short* W2Tb = (unsigned short*)(W + 1475360);         // [8][32][64] bf16
  float* f1b = W + 1484000;                                      // [8][3000]
  float* f2g = W + 1508000;                                      // [8][3000]
  unsigned short* WhT1 = (unsigned short*)(W + 1540000);         // [8][64][3008] bf16 (dead after pvm1)
  unsigned short* t1b = (unsigned short*)(W + 1540000);          // [3000][128] bf16 (after int1)
  unsigned short* h1catb = (unsigned short*)(W + 2320000);       // [2][3000][256] bf16
  float* h2cat = W + 3088000;                                    // [2][3000][128]
  float* t2 = W + 3856000;                                       // [3000][16]
  float* out2 = W + 3904000;                                     // [3000][8]

  // adj -> bitmask
  k_bitmask<<<dim3(1500), 256, 0, stream>>>(adj, bm);
  // casts / weight transposes
  k_cast<<<dim3(750), 256, 0, stream>>>(x, xb, 192000);
  k_wt<64><<<dim3(8, 8), 256, 0, stream>>>(W1, W1Tb, 512, 512);
  k_cast<<<dim3(8), 256, 0, stream>>>(wint1, wint1b, 2048);
  k_cast<<<dim3(4), 256, 0, stream>>>(wfus1, wfus1b, 1024);
  k_wt<32><<<dim3(1, 8), 256, 0, stream>>>(W2, W2Tb, 64, 64);

  // stage 1: Wh1 + f1/f2 + WhT1, fused
  k_xw<64, 512, 1, 0><<<dim3(94, 1, 8), 128, 0, stream>>>(
      xb, 0, W1Tb, 64 * 512, a1, WhT1, (long long)64 * LDT, f1b, f2g, 0, 0);
  // PV stage 1 -> h1catb bf16
  k_pvm<64, 32, true><<<dim3(94, 2, 8), 128, 0, stream>>>(
      WhT1, f1b, f2g, bm, nullptr, h1catb);
  // int1 -> t1b bf16
  k_xw<32, 256, 0, 1><<<dim3(94, 2, 2), 128, 0, stream>>>(
      h1catb, (long long)NNODE * 256, wint1b, 0, bint1, t1b, 0, nullptr, nullptr, 64, 128);
  // fus1 -> out1b bf16
  k_xw<32, 128, 0, 0><<<dim3(94, 2, 1), 128, 0, stream>>>(
      t1b, 0, wfus1b, 0, bfus1, out1b, 0, nullptr, nullptr, 0, 64);

  // stage 2: Wh2 + f1/f2 + WhT2, fused
  k_xw<32, 64, 1, 0><<<dim3(94, 1, 8), 128, 0, stream>>>(
      out1b, 0, W2Tb, 32 * 64, a2, WhT2, (long long)32 * LDT, f1b, f2g, 0, 0);
  // PV stage 2 -> h2cat fp32
  k_pvm<32, 32, false><<<dim3(94, 1, 8), 128, 0, stream>>>(
      WhT2, f1b, f2g, bm, h2cat, nullptr);

  // int2 / fus2 (fp32 tail)
  k_gemm<32, 8, 32, 2, 1, true, 1><<<dim3(94, 1, 2), 128, 0, stream>>>(
      h2cat, (long long)NNODE * 128, 128, wint2, 0, bint2, t2, 8, 16, NNODE, 8, 128);
  k_gemm<32, 8, 16, 2, 1, true, 0><<<dim3(94, 1, 1), 128, 0, stream>>>(
      t2, 0, 16, wfus2, 0, bfus2, out2, 0, 8, NNODE, 8, 16);

  // log_softmax + L1
  k_lsm<<<dim3((NNODE + 255) / 256), 256, 0, stream>>>(out2, out);
  k_l1<<<dim3(1), 256, 0, stream>>>(wfus1, wfus2, out + 24000);
}

// Round 6
// 190.147 us; speedup vs baseline: 7.1834x; 1.4487x over previous
//
#include <hip/hip_runtime.h>
#include <hip/hip_bf16.h>
#include <math.h>

#define NNODE 3000
#define NCHUNK 47  // ceil(3000/64)
#define ALPHA 0.2f
#define LDT 3008   // padded m-stride of WhT (bf16)

typedef __attribute__((ext_vector_type(8))) short short8v;
typedef __attribute__((ext_vector_type(4))) short short4v;
typedef __attribute__((ext_vector_type(4))) float float4v;

static __device__ __forceinline__ short f2b(float x) {
  __hip_bfloat16 b = __float2bfloat16(x);
  return *reinterpret_cast<short*>(&b);
}

// ---------------- adj -> bitmask ----------------
__global__ __launch_bounds__(256)
void k_bitmask(const int* __restrict__ adj, unsigned long long* __restrict__ bm) {
  int row = blockIdx.x * 4 + (threadIdx.x >> 6);
  int lane = threadIdx.x & 63;
  if (row >= 2 * NNODE) return;
  const int* arow = adj + (size_t)row * NNODE;
  unsigned long long* brow = bm + (size_t)row * NCHUNK;
  for (int c = 0; c < NCHUNK; ++c) {
    int m = c * 64 + lane;
    int v = (m < NNODE) ? (arow[m] > 0) : 0;
    unsigned long long mask = __ballot(v);
    if (lane == 0) brow[c] = mask;
  }
}

// ---------------- fp32 -> bf16 cast (8 elems/thread) ----------------
__global__ __launch_bounds__(256)
void k_cast(const float* __restrict__ src, unsigned short* __restrict__ dst,
            int count8) {
  int i = blockIdx.x * 256 + threadIdx.x;
  if (i >= count8) return;
  float4 va = reinterpret_cast<const float4*>(src)[2 * i];
  float4 vb = reinterpret_cast<const float4*>(src)[2 * i + 1];
  short8v w;
  w[0] = f2b(va.x); w[1] = f2b(va.y); w[2] = f2b(va.z); w[3] = f2b(va.w);
  w[4] = f2b(vb.x); w[5] = f2b(vb.y); w[6] = f2b(vb.z); w[7] = f2b(vb.w);
  reinterpret_cast<short8v*>(dst)[i] = w;
}

// ------- weight transpose+cast: src [z][rows][O] f32 -> dst [z][O][ldT] bf16 -------
template <int O>
__global__ __launch_bounds__(256)
void k_wt(const float* __restrict__ src, unsigned short* __restrict__ dst,
          int rows, int ldT) {
  const int z = blockIdx.y;
  const int m0 = blockIdx.x * 64;
  src += (size_t)z * rows * O;
  dst += (size_t)z * O * ldT;
  __shared__ float Lw[64][O + 4];
  const int tid = threadIdx.x;
  for (int idx = tid; idx < 64 * (O / 4); idx += 256) {
    int m = idx / (O / 4), oc = idx % (O / 4);
    float4 v = make_float4(0.f, 0.f, 0.f, 0.f);
    if (m0 + m < rows)
      v = *reinterpret_cast<const float4*>(&src[(size_t)(m0 + m) * O + 4 * oc]);
    *reinterpret_cast<float4*>(&Lw[m][4 * oc]) = v;
  }
  __syncthreads();
  const int o = tid & (O - 1);
  for (int mc = tid / O; mc < 8; mc += 256 / O) {
    short8v w;
#pragma unroll
    for (int j = 0; j < 8; ++j) w[j] = f2b(Lw[8 * mc + j][o]);
    *reinterpret_cast<short8v*>(&dst[(size_t)o * ldT + m0 + 8 * mc]) = w;
  }
}

// ---------------- bf16 MFMA GEMM, 32 rows x OW cols per 128-thr block ----------------
template <int OW, int KC, int MODE, int ACT>
__global__ __launch_bounds__(128)
void k_xw(const unsigned short* __restrict__ Ab, long long boffA,
          const unsigned short* __restrict__ Bb, long long boffB,
          const float* __restrict__ aux,
          unsigned short* __restrict__ Wo,
          long long boffW,
          float* __restrict__ f1o, float* __restrict__ f2o,
          int colStrideZ, int ldC) {
  constexpr int NCT = OW / 16;
  const int z = blockIdx.z;
  const int n0 = blockIdx.x * 32;
  const int ocol0 = blockIdx.y * OW;
  const unsigned short* A = Ab + boffA * z;
  const unsigned short* B = Bb + boffB * z;
  const int tid = threadIdx.x;
  const int l = tid & 63, g = l >> 4, li = l & 15;
  const int r0 = 16 * (tid >> 6);
  __shared__ __align__(16) unsigned short As[32 * 64];
  __shared__ __align__(16) unsigned short Bs[OW * 64];
  float4v acc[NCT];
#pragma unroll
  for (int ct = 0; ct < NCT; ++ct) acc[ct] = {0.f, 0.f, 0.f, 0.f};
  for (int k0 = 0; k0 < KC; k0 += 64) {
    for (int i = tid; i < 256; i += 128) {
      int r = i >> 3, c8 = i & 7;
      uint4 v = {0u, 0u, 0u, 0u};
      if (n0 + r < NNODE)
        v = *reinterpret_cast<const uint4*>(A + (size_t)(n0 + r) * KC + k0 + 8 * c8);
      int boff = (r * 128 + c8 * 16) ^ ((r & 7) << 4);
      *reinterpret_cast<uint4*>(reinterpret_cast<char*>(As) + boff) = v;
    }
    for (int i = tid; i < OW * 8; i += 128) {
      int ro = i >> 3, c8 = i & 7;
      uint4 v = *reinterpret_cast<const uint4*>(B + (size_t)(ocol0 + ro) * KC + k0 + 8 * c8);
      int boff = (ro * 128 + c8 * 16) ^ ((ro & 7) << 4);
      *reinterpret_cast<uint4*>(reinterpret_cast<char*>(Bs) + boff) = v;
    }
    __syncthreads();
#pragma unroll
    for (int q = 0; q < 2; ++q) {
      int aoff = ((r0 + li) * 128 + q * 64 + 16 * g) ^ ((li & 7) << 4);
      short8v afr = *reinterpret_cast<const short8v*>(
          reinterpret_cast<const char*>(As) + aoff);
#pragma unroll
      for (int ct = 0; ct < NCT; ++ct) {
        int orow = ct * 16 + li;
        int boff = (orow * 128 + q * 64 + 16 * g) ^ ((li & 7) << 4);
        short8v bfr = *reinterpret_cast<const short8v*>(
            reinterpret_cast<const char*>(Bs) + boff);
        acc[ct] = __builtin_amdgcn_mfma_f32_16x16x32_bf16(afr, bfr, acc[ct], 0, 0, 0);
      }
    }
    __syncthreads();
  }
  if (MODE == 1) {
    const float* av = aux + (size_t)z * 2 * OW;
    float p1[4] = {0.f, 0.f, 0.f, 0.f}, p2[4] = {0.f, 0.f, 0.f, 0.f};
#pragma unroll
    for (int ct = 0; ct < NCT; ++ct) {
      float a1v = av[ct * 16 + li];
      float a2v = av[OW + ct * 16 + li];
#pragma unroll
      for (int j = 0; j < 4; ++j) {
        p1[j] += acc[ct][j] * a1v;
        p2[j] += acc[ct][j] * a2v;
      }
    }
#pragma unroll
    for (int off = 1; off < 16; off <<= 1) {
#pragma unroll
      for (int j = 0; j < 4; ++j) {
        p1[j] += __shfl_xor(p1[j], off);
        p2[j] += __shfl_xor(p2[j], off);
      }
    }
    unsigned short* WT = Wo + boffW * z;
#pragma unroll
    for (int ct = 0; ct < NCT; ++ct) {
      short4v w;
#pragma unroll
      for (int j = 0; j < 4; ++j) w[j] = f2b(acc[ct][j]);
      *reinterpret_cast<short4v*>(
          &WT[(size_t)(ocol0 + ct * 16 + li) * LDT + n0 + r0 + 4 * g]) = w;
    }
    if (li == 0) {
#pragma unroll
      for (int j = 0; j < 4; ++j) {
        int n = n0 + r0 + 4 * g + j;
        if (n < NNODE) {
          f1o[(size_t)z * NNODE + n] = p1[j];
          f2o[(size_t)z * NNODE + n] = p2[j];
        }
      }
    }
  } else {
#pragma unroll
    for (int ct = 0; ct < NCT; ++ct) {
      float b = aux[ocol0 + ct * 16 + li];
#pragma unroll
      for (int j = 0; j < 4; ++j) {
        int n = n0 + r0 + 4 * g + j;
        if (n < NNODE) {
          float v = acc[ct][j] + b;
          if (ACT == 1) v = v > 0.f ? v : (__expf(v) - 1.f);
          Wo[(size_t)n * ldC + z * colStrideZ + ocol0 + ct * 16 + li] = (unsigned short)f2b(v);
        }
      }
    }
  }
}

// ---------------- MFMA PV with K-split: partial C + partial rowsum ----------------
// 256 thr, 64 rows, full O cols. Preloaded bitmask/f2/f1 slabs; dbuf Wh tile.
template <int O, int CPS>
__global__ __launch_bounds__(256)
void k_pvs(const unsigned short* __restrict__ WhT,
           const float* __restrict__ f1, const float* __restrict__ f2,
           const unsigned long long* __restrict__ bm,
           float* __restrict__ Cpart, float* __restrict__ rsum) {
  constexpr int NCT = O / 16;
  const int z = blockIdx.z, a = z >> 2;
  const int ks = blockIdx.y;
  const int n0 = blockIdx.x * 64;
  const int kc0 = ks * CPS;
  const int nch = (NCHUNK - kc0 < CPS) ? (NCHUNK - kc0) : CPS;
  const int tid = threadIdx.x;
  const int l = tid & 63, li = l & 15, g = l >> 4;
  const int r0 = 16 * (tid >> 6);
  const unsigned short* WT = WhT + (size_t)z * O * LDT;
  const float* f2B = f2 + (size_t)z * NNODE;
  const unsigned long long* bmA = bm + (size_t)a * NNODE * NCHUNK;
  __shared__ __align__(16) unsigned short Whs[2][O * 64];
  __shared__ float F2s[CPS * 64];
  __shared__ unsigned long long BwS[64][CPS + 1];
  __shared__ float F1s[64];
  // ---- preload metadata slabs ----
  if (tid < 64) {
    int n = n0 + tid;
    F1s[tid] = (n < NNODE) ? f1[(size_t)z * NNODE + n] : 0.f;
  }
  for (int i = tid; i < 64 * CPS; i += 256) {
    int r = i / CPS, c = i % CPS;
    int n = n0 + r;
    BwS[r][c] = (n < NNODE && c < nch) ? bmA[(size_t)n * NCHUNK + kc0 + c] : 0ULL;
  }
  for (int i = tid; i < CPS * 64; i += 256) {
    int m = kc0 * 64 + i;
    F2s[i] = (m < NNODE && i < nch * 64) ? f2B[m] : 0.f;
  }
  float4v acc[NCT];
#pragma unroll
  for (int ct = 0; ct < NCT; ++ct) acc[ct] = {0.f, 0.f, 0.f, 0.f};
  float rs = 0.f;
  // stage tile helper
  auto stage = [&](int t, int buf) {
    for (int i = tid; i < O * 8; i += 256) {
      int ro = i >> 3, c8 = i & 7;
      uint4 v = *reinterpret_cast<const uint4*>(
          WT + (size_t)ro * LDT + (size_t)(kc0 + t) * 64 + 8 * c8);
      int boff = (ro * 128 + c8 * 16) ^ ((ro & 7) << 4);
      *reinterpret_cast<uint4*>(reinterpret_cast<char*>(Whs[buf]) + boff) = v;
    }
  };
  stage(0, 0);
  __syncthreads();  // covers preloads + tile 0
  for (int t = 0; t < nch; ++t) {
    int buf = t & 1;
    if (t + 1 < nch) stage(t + 1, buf ^ 1);
    // ---- generate P A-frags in registers ----
    const unsigned long long bwr = BwS[r0 + li][t];
    const float f1v = F1s[r0 + li];
    short8v afr[2];
#pragma unroll
    for (int q = 0; q < 2; ++q) {
      int koff = 32 * q + 8 * g;
      unsigned bits = (unsigned)(bwr >> koff) & 0xffu;
      const float4 fa = *reinterpret_cast<const float4*>(&F2s[t * 64 + koff]);
      const float4 fb = *reinterpret_cast<const float4*>(&F2s[t * 64 + koff + 4]);
      float f2v[8] = {fa.x, fa.y, fa.z, fa.w, fb.x, fb.y, fb.z, fb.w};
#pragma unroll
      for (int e = 0; e < 8; ++e) {
        float tt = f1v + f2v[e];
        tt = fmaxf(tt, ALPHA * tt);
        float p = __expf(tt);
        p = (bits & (1u << e)) ? p : 0.f;
        rs += p;
        afr[q][e] = f2b(p);
      }
    }
    // ---- B-frags + MFMA ----
#pragma unroll
    for (int ct = 0; ct < NCT; ++ct) {
      int orow = ct * 16 + li;
#pragma unroll
      for (int q = 0; q < 2; ++q) {
        int boff = (orow * 128 + q * 64 + 16 * g) ^ ((li & 7) << 4);
        short8v bfr = *reinterpret_cast<const short8v*>(
            reinterpret_cast<const char*>(Whs[buf]) + boff);
        acc[ct] = __builtin_amdgcn_mfma_f32_16x16x32_bf16(afr[q], bfr, acc[ct], 0, 0, 0);
      }
    }
    __syncthreads();  // buf consumed; buf^1 staged
  }
  // ---- partial rowsum reduce ----
  rs += __shfl_xor(rs, 16);
  rs += __shfl_xor(rs, 32);
  // ---- write partials ----
  float* Cp = Cpart + ((size_t)ks * 8 + z) * NNODE * O;
#pragma unroll
  for (int j = 0; j < 4; ++j) {
    int n = n0 + r0 + 4 * g + j;
    if (n < NNODE) {
#pragma unroll
      for (int ct = 0; ct < NCT; ++ct)
        Cp[(size_t)n * O + ct * 16 + li] = acc[ct][j];
    }
  }
  if (l < 16) {
    int n = n0 + r0 + li;
    if (n < NNODE) rsum[((size_t)ks * 8 + z) * NNODE + n] = rs;
  }
}

// ---------------- PV reduce: sum partials, normalize, ELU, head-concat ----------------
template <int O, int KS, bool WB16>
__global__ __launch_bounds__(256)
void k_pvred(const float* __restrict__ Cpart, const float* __restrict__ rsum,
             float* __restrict__ Cf, unsigned short* __restrict__ Cb) {
  constexpr int C4 = O / 4;
  int idx = blockIdx.x * 256 + threadIdx.x;
  if (idx >= 8 * NNODE * C4) return;
  int zn = idx / C4, c4 = idx % C4;
  int z = zn / NNODE, n = zn % NNODE;
  int a = z >> 2, h = z & 3;
  float s = 0.f;
#pragma unroll
  for (int k = 0; k < KS; ++k) s += rsum[(size_t)k * 8 * NNODE + zn];
  float inv = (s > 0.f) ? 1.f / s : 0.f;
  float accv[4] = {0.f, 0.f, 0.f, 0.f};
#pragma unroll
  for (int k = 0; k < KS; ++k) {
    float4 v = *reinterpret_cast<const float4*>(
        Cpart + (size_t)k * 8 * NNODE * O + (size_t)zn * O + 4 * c4);
    accv[0] += v.x; accv[1] += v.y; accv[2] += v.z; accv[3] += v.w;
  }
  size_t base = ((size_t)a * NNODE + n) * (4 * O) + (size_t)h * O + 4 * c4;
  if (WB16) {
    short4v w;
#pragma unroll
    for (int j = 0; j < 4; ++j) {
      float v = accv[j] * inv;
      v = v > 0.f ? v : (__expf(v) - 1.f);
      w[j] = f2b(v);
    }
    *reinterpret_cast<short4v*>(Cb + base) = w;
  } else {
    float4 w;
    float* wp = &w.x;
#pragma unroll
    for (int j = 0; j < 4; ++j) {
      float v = accv[j] * inv;
      wp[j] = v > 0.f ? v : (__expf(v) - 1.f);
    }
    *reinterpret_cast<float4*>(Cf + base) = w;
  }
}

// ---------------- generic tiled fp32 GEMM (tail layers) ----------------
template <int BM, int BN, int BK, int TM, int TN, bool BT, int ACT>
__global__ __launch_bounds__((BM / TM) * (BN / TN))
void k_gemm(const float* __restrict__ A, long long boffA, int ldA,
            const float* __restrict__ B, long long boffB,
            const float* __restrict__ bias,
            float* __restrict__ C, long long boffC, int ldC,
            int M, int N, int K) {
  constexpr int NT = (BM / TM) * (BN / TN);
  constexpr int NCG = BN / TN;
  const int z = blockIdx.z;
  A += boffA * z;
  B += boffB * z;
  C += boffC * z;
  const int m0 = blockIdx.x * BM;
  const int n0 = blockIdx.y * BN;
  __shared__ float As[BK][BM + 4];
  __shared__ float Bs[BK][BN + 4];
  const int tid = threadIdx.x;
  const int trow = tid / NCG, tcol = tid % NCG;
  float acc[TM][TN] = {};
  for (int k0 = 0; k0 < K; k0 += BK) {
    for (int i = tid; i < BM * BK; i += NT) {
      int r = i / BK, c = i % BK;
      int gm = m0 + r;
      As[c][r] = (gm < M) ? A[(size_t)gm * ldA + (k0 + c)] : 0.f;
    }
    if (!BT) {
      for (int i = tid; i < BK * BN; i += NT) {
        int r = i / BN, c = i % BN;
        Bs[r][c] = B[(size_t)(k0 + r) * N + (n0 + c)];
      }
    } else {
      for (int i = tid; i < BK * BN; i += NT) {
        int r = i % BK, c = i / BK;
        Bs[r][c] = B[(size_t)(n0 + c) * K + (k0 + r)];
      }
    }
    __syncthreads();
#pragma unroll 8
    for (int kk = 0; kk < BK; ++kk) {
      float ar[TM], br[TN];
#pragma unroll
      for (int i2 = 0; i2 < TM; ++i2) ar[i2] = As[kk][trow * TM + i2];
#pragma unroll
      for (int j = 0; j < TN; ++j) br[j] = Bs[kk][tcol * TN + j];
#pragma unroll
      for (int i2 = 0; i2 < TM; ++i2)
#pragma unroll
        for (int j = 0; j < TN; ++j)
          acc[i2][j] = fmaf(ar[i2], br[j], acc[i2][j]);
    }
    __syncthreads();
  }
#pragma unroll
  for (int i2 = 0; i2 < TM; ++i2) {
    int gm = m0 + trow * TM + i2;
    if (gm >= M) continue;
#pragma unroll
    for (int j = 0; j < TN; ++j) {
      int gn = n0 + tcol * TN + j;
      float v = acc[i2][j];
      if (bias) v += bias[gn];
      if (ACT == 1) v = v > 0.f ? v : (__expf(v) - 1.f);
      C[(size_t)gm * ldC + gn] = v;
    }
  }
}

// ---------------- log_softmax rows of 8 ----------------
__global__ __launch_bounds__(256)
void k_lsm(const float* __restrict__ out2, float* __restrict__ out) {
  int n = blockIdx.x * blockDim.x + threadIdx.x;
  if (n >= NNODE) return;
  const float* r = out2 + (size_t)n * 8;
  float mx = r[0];
#pragma unroll
  for (int j = 1; j < 8; ++j) mx = fmaxf(mx, r[j]);
  float s = 0.f;
#pragma unroll
  for (int j = 0; j < 8; ++j) s += __expf(r[j] - mx);
  float ls = __logf(s) + mx;
#pragma unroll
  for (int j = 0; j < 8; ++j) out[(size_t)n * 8 + j] = r[j] - ls;
}

// ---------------- L1 scalar ----------------
__global__ __launch_bounds__(256)
void k_l1(const float* __restrict__ wfus1, const float* __restrict__ wfus2,
          float* __restrict__ o) {
  __shared__ float red[256];
  int tid = threadIdx.x;
  float s1 = 0.f, s2 = 0.f;
  for (int i = tid; i < 64 * 128; i += 256) s1 += fabsf(wfus1[i]);
  if (tid < 128) s2 = fabsf(wfus2[tid]);
  red[tid] = s1 / 8192.f + s2 / 128.f;
  __syncthreads();
  for (int off = 128; off; off >>= 1) {
    if (tid < off) red[tid] += red[tid + off];
    __syncthreads();
  }
  if (tid == 0) o[0] = red[0];
}

extern "C" void kernel_launch(void* const* d_in, const int* in_sizes, int n_in,
                              void* d_out, int out_size, void* d_ws, size_t ws_size,
                              hipStream_t stream) {
  const float* x = (const float*)d_in[0];
  const int* adj = (const int*)d_in[1];
  const float* W1 = (const float*)d_in[2];
  const float* a1 = (const float*)d_in[3];
  const float* W2 = (const float*)d_in[4];
  const float* a2 = (const float*)d_in[5];
  const float* wint1 = (const float*)d_in[6];
  const float* bint1 = (const float*)d_in[7];
  const float* wfus1 = (const float*)d_in[8];
  const float* bfus1 = (const float*)d_in[9];
  const float* wint2 = (const float*)d_in[10];
  const float* bint2 = (const float*)d_in[11];
  const float* wfus2 = (const float*)d_in[12];
  const float* bfus2 = (const float*)d_in[13];
  float* out = (float*)d_out;

  // workspace layout (float offsets); peak 5,517,600 floats = 22.1 MB
  float* W = (float*)d_ws;
  unsigned long long* bm = (unsigned long long*)d_ws;          // 0..564000
  unsigned short* xb = (unsigned short*)(W + 564000);          // [3000][512] bf16, dead after xw1
  unsigned short* h1catb = (unsigned short*)(W + 564000);      // [2][3000][256] bf16 (after reduce1)
  float* h2cat = W + 564000;                                   // [2][3000][128] f32 (after reduce2)
  unsigned short* W1Tb = (unsigned short*)(W + 1332000);       // [8][64][512] bf16
  unsigned short* wint1b = (unsigned short*)(W + 1463072);     // [64][256] bf16
  unsigned short* wfus1b = (unsigned short*)(W + 1471264);     // [64][128] bf16
  unsigned short* W2Tb = (unsigned short*)(W + 1475360);       // [8][32][64] bf16
  float* f1b = W + 1483552;                                    // [8][3000]
  float* f2g = W + 1507552;                                    // [8][3000]
  unsigned short* WhT1 = (unsigned short*)(W + 1531552);       // [8][64][3008] bf16, dead after pvs1
  unsigned short* t1b = (unsigned short*)(W + 1531552);        // [3000][128] bf16 (after int1)
  unsigned short* out1b = (unsigned short*)(W + 1723552);      // [3000][64] bf16
  unsigned short* WhT2 = (unsigned short*)(W + 1819552);       // [8][32][3008] bf16
  float* t2 = W + 2301600;                                     // [3000][16]
  float* out2 = W + 2349600;                                   // [3000][8]
  float* rsumw = W + 2373600;                                  // [3][8][3000]
  float* Cpart = W + 2445600;                                  // [2][8][3000][64] / [3][8][3000][32]

  // adj -> bitmask
  k_bitmask<<<dim3(1500), 256, 0, stream>>>(adj, bm);
  // casts / weight transposes
  k_cast<<<dim3(750), 256, 0, stream>>>(x, xb, 192000);
  k_wt<64><<<dim3(8, 8), 256, 0, stream>>>(W1, W1Tb, 512, 512);
  k_cast<<<dim3(8), 256, 0, stream>>>(wint1, wint1b, 2048);
  k_cast<<<dim3(4), 256, 0, stream>>>(wfus1, wfus1b, 1024);
  k_wt<32><<<dim3(1, 8), 256, 0, stream>>>(W2, W2Tb, 64, 64);

  // stage 1: Wh1 + f1/f2 + WhT1, fused
  k_xw<64, 512, 1, 0><<<dim3(94, 1, 8), 128, 0, stream>>>(
      xb, 0, W1Tb, 64 * 512, a1, WhT1, (long long)64 * LDT, f1b, f2g, 0, 0);
  // PV stage 1 (K-split 2) -> partials -> h1catb bf16
  k_pvs<64, 24><<<dim3(47, 2, 8), 256, 0, stream>>>(WhT1, f1b, f2g, bm, Cpart, rsumw);
  k_pvred<64, 2, true><<<dim3(1500), 256, 0, stream>>>(Cpart, rsumw, nullptr, h1catb);
  // int1 -> t1b bf16
  k_xw<32, 256, 0, 1><<<dim3(94, 2, 2), 128, 0, stream>>>(
      h1catb, (long long)NNODE * 256, wint1b, 0, bint1, t1b, 0, nullptr, nullptr, 64, 128);
  // fus1 -> out1b bf16
  k_xw<32, 128, 0, 0><<<dim3(94, 2, 1), 128, 0, stream>>>(
      t1b, 0, wfus1b, 0, bfus1, out1b, 0, nullptr, nullptr, 0, 64);

  // stage 2: Wh2 + f1/f2 + WhT2, fused
  k_xw<32, 64, 1, 0><<<dim3(94, 1, 8), 128, 0, stream>>>(
      out1b, 0, W2Tb, 32 * 64, a2, WhT2, (long long)32 * LDT, f1b, f2g, 0, 0);
  // PV stage 2 (K-split 3) -> partials -> h2cat fp32
  k_pvs<32, 16><<<dim3(47, 3, 8), 256, 0, stream>>>(WhT2, f1b, f2g, bm, Cpart, rsumw);
  k_pvred<32, 3, false><<<dim3(750), 256, 0, stream>>>(Cpart, rsumw, h2cat, nullptr);

  // int2 / fus2 (fp32 tail)
  k_gemm<32, 8, 32, 2, 1, true, 1><<<dim3(94, 1, 2), 128, 0, stream>>>(
      h2cat, (long long)NNODE * 128, 128, wint2, 0, bint2, t2, 8, 16, NNODE, 8, 128);
  k_gemm<32, 8, 16, 2, 1, true, 0><<<dim3(94, 1, 1), 128, 0, stream>>>(
      t2, 0, 16, wfus2, 0, bfus2, out2, 0, 8, NNODE, 8, 16);

  // log_softmax + L1
  k_lsm<<<dim3((NNODE + 255) / 256), 256, 0, stream>>>(out2, out);
  k_l1<<<dim3(1), 256, 0, stream>>>(wfus1, wfus2, out + 24000);
}